// Round 1
// baseline (735.186 us; speedup 1.0000x reference)
//
#include <hip/hip_runtime.h>
#include <cstdint>
#include <cstddef>

#define NEG_SLOPE 0.2f

// ---------------------------------------------------------------------------
// Problem shape (from reference): N=100000, F_in=128, H=4, C1=32 (HC=128),
// C2=16, E=1600000 (+N self-loops). All f32 except edge_index (int32/int64).
// Strategy: CSR-by-dst build (int atomics only), then gather-side aggregation
// (no float atomics). GEMMs are f32 vector (no fp32 MFMA on CDNA4).
// ---------------------------------------------------------------------------

__device__ __forceinline__ int edge_at(const void* ei, long long idx, int is64) {
    if (is64) return (int)((const long long*)ei)[idx];
    return ((const int*)ei)[idx];
}

// Detect whether edge_index is int64 or int32 by probing high words.
// Values are in [0, 100000) so int64 high words are all zero; int32 data at
// those positions is uniform in [0,1e5) -> P(zero) ~ 1e-5.
__global__ void detect_fmt_kernel(const void* ei, int* flag) {
    if (threadIdx.x == 0 && blockIdx.x == 0) {
        const unsigned* u = (const unsigned*)ei;
        int zc = 0;
        for (int i = 0; i < 128; ++i) zc += (u[2 * i + 1] == 0u);
        *flag = (zc >= 100) ? 1 : 0;
    }
}

// ---------------------------------------------------------------------------
// GEMM1: h1[N,128] = x[N,128] @ W1[128,128].  f32 vector, LDS-tiled.
// BM=128, BN=128 (full), BK=32, 256 threads, 8x8 per-thread register tile.
// ---------------------------------------------------------------------------
__global__ __launch_bounds__(256) void gemm1_kernel(
    const float* __restrict__ x, const float* __restrict__ W,
    float* __restrict__ h1, int N) {
    __shared__ float As[128][33];   // pad 33: a-frag reads land on distinct banks
    __shared__ float Bs[32][128];
    const int tid = threadIdx.x;
    const int tx = tid & 15, ty = tid >> 4;
    const int base = blockIdx.x * 128;

    float acc[8][8];
#pragma unroll
    for (int i = 0; i < 8; ++i)
#pragma unroll
        for (int j = 0; j < 8; ++j) acc[i][j] = 0.f;

    for (int kb = 0; kb < 128; kb += 32) {
        {   // stage x tile [128 rows][32 cols]
            const int r0 = tid >> 3;   // 0..31
            const int q  = tid & 7;    // 0..7 -> cols q*4..q*4+3
#pragma unroll
            for (int p = 0; p < 4; ++p) {
                int r = r0 + p * 32;
                int gr = base + r;
                float4 v = make_float4(0.f, 0.f, 0.f, 0.f);
                if (gr < N) v = *(const float4*)(x + (size_t)gr * 128 + kb + q * 4);
                As[r][q * 4 + 0] = v.x; As[r][q * 4 + 1] = v.y;
                As[r][q * 4 + 2] = v.z; As[r][q * 4 + 3] = v.w;
            }
        }
        {   // stage W tile [32 k][128 cols]
            const int k0 = tid >> 5;   // 0..7
            const int f  = tid & 31;   // float4 col index
#pragma unroll
            for (int p = 0; p < 4; ++p) {
                int kk = k0 + p * 8;
                float4 v = *(const float4*)(W + (size_t)(kb + kk) * 128 + f * 4);
                *(float4*)&Bs[kk][f * 4] = v;
            }
        }
        __syncthreads();
#pragma unroll 4
        for (int kk = 0; kk < 32; ++kk) {
            float a[8];
#pragma unroll
            for (int i = 0; i < 8; ++i) a[i] = As[ty * 8 + i][kk];
            // cols tx*4..+3 and 64+tx*4..+3 : 2-way LDS aliasing only (free)
            float4 b0 = *(const float4*)&Bs[kk][tx * 4];
            float4 b1 = *(const float4*)&Bs[kk][64 + tx * 4];
            float b[8] = {b0.x, b0.y, b0.z, b0.w, b1.x, b1.y, b1.z, b1.w};
#pragma unroll
            for (int i = 0; i < 8; ++i)
#pragma unroll
                for (int j = 0; j < 8; ++j)
                    acc[i][j] = fmaf(a[i], b[j], acc[i][j]);
        }
        __syncthreads();
    }
#pragma unroll
    for (int i = 0; i < 8; ++i) {
        int gr = base + ty * 8 + i;
        if (gr < N) {
            float4 o0 = make_float4(acc[i][0], acc[i][1], acc[i][2], acc[i][3]);
            float4 o1 = make_float4(acc[i][4], acc[i][5], acc[i][6], acc[i][7]);
            *(float4*)(h1 + (size_t)gr * 128 + tx * 4) = o0;
            *(float4*)(h1 + (size_t)gr * 128 + 64 + tx * 4) = o1;
        }
    }
}

// alpha_src1[n,h] = sum_c h1[n,h*32+c]*a_src1[h*32+c]; same for dst.
// 256 threads = 2 nodes x 128 channels; 32-lane shuffle reduce per head.
__global__ void alpha1_kernel(const float* __restrict__ h1,
                              const float* __restrict__ a_src,
                              const float* __restrict__ a_dst,
                              float* __restrict__ asrc, float* __restrict__ adst,
                              int N) {
    int tid = threadIdx.x;
    int n = blockIdx.x * 2 + (tid >> 7);
    int c = tid & 127;
    if (n >= N) return;
    float v = h1[(size_t)n * 128 + c];
    float s1 = v * a_src[c];
    float s2 = v * a_dst[c];
#pragma unroll
    for (int off = 16; off; off >>= 1) {
        s1 += __shfl_xor(s1, off, 32);
        s2 += __shfl_xor(s2, off, 32);
    }
    if ((c & 31) == 0) {
        int h = c >> 5;
        asrc[n * 4 + h] = s1;
        adst[n * 4 + h] = s2;
    }
}

// ---------------------------------------------------------------------------
// CSR build: degree (self-loop => init 1) -> exclusive scan -> scatter srcs
// ---------------------------------------------------------------------------
__global__ void deg_init_kernel(int* deg, int* cursor, int N) {
    int i = blockIdx.x * 256 + threadIdx.x;
    if (i < N) { deg[i] = 1; cursor[i] = 0; }
}

__global__ void hist_kernel(const void* ei, int* deg, int E, const int* flag) {
    int i = blockIdx.x * 256 + threadIdx.x;
    if (i < E) {
        int is64 = *flag;
        int d = edge_at(ei, (long long)E + i, is64);
        atomicAdd(&deg[d], 1);
    }
}

__global__ void reduce_kernel(const int* __restrict__ deg, int* bsums, int N) {
    __shared__ int s[256];
    int tid = threadIdx.x;
    int base = blockIdx.x * 1024 + tid * 4;
    int t = 0;
#pragma unroll
    for (int u = 0; u < 4; ++u) { int idx = base + u; if (idx < N) t += deg[idx]; }
    s[tid] = t;
    __syncthreads();
    for (int off = 128; off; off >>= 1) {
        if (tid < off) s[tid] += s[tid + off];
        __syncthreads();
    }
    if (tid == 0) bsums[blockIdx.x] = s[0];
}

__global__ void scan_bsums_kernel(int* bsums, int* rowptr, int nb, int N) {
    if (threadIdx.x == 0 && blockIdx.x == 0) {
        int run = 0;
        for (int b = 0; b < nb; ++b) { int t = bsums[b]; bsums[b] = run; run += t; }
        rowptr[N] = run;
    }
}

__global__ void scan_write_kernel(const int* __restrict__ deg,
                                  const int* __restrict__ bsums,
                                  int* __restrict__ rowptr, int N) {
    __shared__ int s[256];
    int tid = threadIdx.x;
    int base_i = blockIdx.x * 1024 + tid * 4;
    int v[4]; int t = 0;
#pragma unroll
    for (int u = 0; u < 4; ++u) {
        int idx = base_i + u;
        v[u] = (idx < N) ? deg[idx] : 0;
        t += v[u];
    }
    s[tid] = t;
    __syncthreads();
    for (int off = 1; off < 256; off <<= 1) {   // Hillis-Steele inclusive
        int tv = (tid >= off) ? s[tid - off] : 0;
        __syncthreads();
        s[tid] += tv;
        __syncthreads();
    }
    int excl = (tid == 0) ? 0 : s[tid - 1];
    int p = bsums[blockIdx.x] + excl;
#pragma unroll
    for (int u = 0; u < 4; ++u) {
        int idx = base_i + u;
        if (idx < N) rowptr[idx] = p;
        p += v[u];
    }
}

__global__ void scatter_kernel(const void* ei, const int* __restrict__ rowptr,
                               int* cursor, int* __restrict__ srcs,
                               int E, int ET, const int* flag) {
    int i = blockIdx.x * 256 + threadIdx.x;
    if (i < ET) {
        int is64 = *flag;
        int s, d;
        if (i < E) {
            s = edge_at(ei, i, is64);
            d = edge_at(ei, (long long)E + i, is64);
        } else {
            s = d = i - E;   // self-loops appended at the end (order-agnostic)
        }
        int pos = rowptr[d] + atomicAdd(&cursor[d], 1);
        srcs[pos] = s;
    }
}

// ---------------------------------------------------------------------------
// Layer-1 aggregation: one 128-thread block per dst node; thread = channel.
// Phase A: per-head max (all threads redundantly, broadcast loads).
// Phase B: denom + weighted h1 gather-accumulate (scalar acc per thread).
// Epilogue: +b1, ELU -> g.
// ---------------------------------------------------------------------------
__global__ __launch_bounds__(128) void agg1_kernel(
    const float* __restrict__ h1, const float* __restrict__ asrc,
    const float* __restrict__ adst, const int* __restrict__ rowptr,
    const int* __restrict__ srcs, const float* __restrict__ b1,
    float* __restrict__ g, int N) {
    int d = blockIdx.x;
    int tid = threadIdx.x;
    int h = tid >> 5;
    int start = rowptr[d], end = rowptr[d + 1];
    float ad = adst[d * 4 + h];
    float m = -1e30f;
    for (int j = start; j < end; ++j) {
        int s = srcs[j];
        float l = asrc[s * 4 + h] + ad;
        l = (l > 0.f) ? l : NEG_SLOPE * l;
        m = fmaxf(m, l);
    }
    float acc = 0.f, lsum = 0.f;
    for (int j = start; j < end; ++j) {
        int s = srcs[j];
        float l = asrc[s * 4 + h] + ad;
        l = (l > 0.f) ? l : NEG_SLOPE * l;
        float w = __expf(l - m);
        lsum += w;
        acc = fmaf(w, h1[(size_t)s * 128 + tid], acc);
    }
    float r = acc / lsum + b1[tid];
    g[(size_t)d * 128 + tid] = (r > 0.f) ? r : expm1f(r);
}

// ---------------------------------------------------------------------------
// GEMM2 + alpha2: h2[N,16] = g[N,128] @ W2[128,16]; alpha2 via 16-lane reduce.
// 256 threads = 16 nodes x 16 channels; g tile + W2 staged in LDS.
// ---------------------------------------------------------------------------
__global__ __launch_bounds__(256) void gemm2_kernel(
    const float* __restrict__ g, const float* __restrict__ W2,
    const float* __restrict__ a_src2, const float* __restrict__ a_dst2,
    float* __restrict__ h2, float* __restrict__ asrc2, float* __restrict__ adst2,
    int N) {
    __shared__ float W2s[128 * 16];
    __shared__ float gs[16][132];   // pad 132: 4 node-rows hit distinct banks
    int tid = threadIdx.x;
#pragma unroll
    for (int u = 0; u < 8; ++u) W2s[u * 256 + tid] = W2[u * 256 + tid];
    int base = blockIdx.x * 16;
#pragma unroll
    for (int p = 0; p < 2; ++p) {
        int q = tid + p * 256;         // float4 index 0..511
        int r = q >> 5, c4 = q & 31;
        int gr = base + r;
        float4 v = make_float4(0.f, 0.f, 0.f, 0.f);
        if (gr < N) v = *(const float4*)(g + (size_t)gr * 128 + c4 * 4);
        *(float4*)&gs[r][c4 * 4] = v;
    }
    __syncthreads();
    int ln = tid >> 4, c = tid & 15;
    int n = base + ln;
    float acc = 0.f;
#pragma unroll 8
    for (int k = 0; k < 128; ++k)
        acc = fmaf(gs[ln][k], W2s[k * 16 + c], acc);
    float s1 = acc * a_src2[c];
    float s2 = acc * a_dst2[c];
#pragma unroll
    for (int off = 8; off; off >>= 1) {
        s1 += __shfl_xor(s1, off, 16);
        s2 += __shfl_xor(s2, off, 16);
    }
    if (n < N) {
        h2[(size_t)n * 16 + c] = acc;
        if (c == 0) { asrc2[n] = s1; adst2[n] = s2; }
    }
}

// Layer-2 aggregation: 64-thread block = 4 nodes x 16 channels.
__global__ __launch_bounds__(64) void agg2_kernel(
    const float* __restrict__ h2, const float* __restrict__ asrc2,
    const float* __restrict__ adst2, const int* __restrict__ rowptr,
    const int* __restrict__ srcs, const float* __restrict__ b2,
    float* __restrict__ out, int N) {
    int tid = threadIdx.x;
    int d = blockIdx.x * 4 + (tid >> 4);
    int c = tid & 15;
    if (d >= N) return;
    int start = rowptr[d], end = rowptr[d + 1];
    float ad = adst2[d];
    float m = -1e30f;
    for (int j = start; j < end; ++j) {
        float l = asrc2[srcs[j]] + ad;
        l = (l > 0.f) ? l : NEG_SLOPE * l;
        m = fmaxf(m, l);
    }
    float acc = 0.f, lsum = 0.f;
    for (int j = start; j < end; ++j) {
        int s = srcs[j];
        float l = asrc2[s] + ad;
        l = (l > 0.f) ? l : NEG_SLOPE * l;
        float w = __expf(l - m);
        lsum += w;
        acc = fmaf(w, h2[(size_t)s * 16 + c], acc);
    }
    out[(size_t)d * 16 + c] = acc / lsum + b2[c];
}

// ---------------------------------------------------------------------------
extern "C" void kernel_launch(void* const* d_in, const int* in_sizes, int n_in,
                              void* d_out, int out_size, void* d_ws, size_t ws_size,
                              hipStream_t stream) {
    const float* x      = (const float*)d_in[0];
    const void*  ei     = d_in[1];
    const float* W1     = (const float*)d_in[2];
    const float* a_src1 = (const float*)d_in[3];
    const float* a_dst1 = (const float*)d_in[4];
    const float* b1     = (const float*)d_in[5];
    const float* W2     = (const float*)d_in[6];
    const float* a_src2 = (const float*)d_in[7];
    const float* a_dst2 = (const float*)d_in[8];
    const float* b2     = (const float*)d_in[9];

    const int N  = in_sizes[0] / 128;   // 100000
    const int E  = in_sizes[1] / 2;     // 1600000
    const int ET = E + N;

    // workspace layout (all 256B-aligned); total ~114 MB
    char* w = (char*)d_ws;
    size_t off = 0;
    auto alloc = [&](size_t bytes) -> char* {
        char* p = w + off;
        off = (off + bytes + 255) & ~(size_t)255;
        return p;
    };
    float* h1     = (float*)alloc((size_t)N * 128 * 4);
    float* g      = (float*)alloc((size_t)N * 128 * 4);
    float* asrc1  = (float*)alloc((size_t)N * 4 * 4);
    float* adst1  = (float*)alloc((size_t)N * 4 * 4);
    int*   deg    = (int*)alloc((size_t)N * 4);
    int*   cursor = (int*)alloc((size_t)N * 4);
    int*   rowptr = (int*)alloc((size_t)(N + 1) * 4);
    int*   srcs   = (int*)alloc((size_t)ET * 4);
    int*   bsums  = (int*)alloc(4096);
    int*   flag   = (int*)alloc(256);
    // layer-2 buffers alias h1's region (h1 is dead after agg1)
    float* h2    = h1;
    float* asrc2 = h1 + (size_t)N * 16;
    float* adst2 = asrc2 + N;

    const int nb = (N + 1023) / 1024;

    detect_fmt_kernel<<<1, 1, 0, stream>>>(ei, flag);
    gemm1_kernel<<<(N + 127) / 128, 256, 0, stream>>>(x, W1, h1, N);
    alpha1_kernel<<<(N + 1) / 2, 256, 0, stream>>>(h1, a_src1, a_dst1, asrc1, adst1, N);
    deg_init_kernel<<<(N + 255) / 256, 256, 0, stream>>>(deg, cursor, N);
    hist_kernel<<<(E + 255) / 256, 256, 0, stream>>>(ei, deg, E, flag);
    reduce_kernel<<<nb, 256, 0, stream>>>(deg, bsums, N);
    scan_bsums_kernel<<<1, 1, 0, stream>>>(bsums, rowptr, nb, N);
    scan_write_kernel<<<nb, 256, 0, stream>>>(deg, bsums, rowptr, N);
    scatter_kernel<<<(ET + 255) / 256, 256, 0, stream>>>(ei, rowptr, cursor, srcs, E, ET, flag);
    agg1_kernel<<<N, 128, 0, stream>>>(h1, asrc1, adst1, rowptr, srcs, b1, g, N);
    gemm2_kernel<<<(N + 15) / 16, 256, 0, stream>>>(g, W2, a_src2, a_dst2, h2, asrc2, adst2, N);
    agg2_kernel<<<(N + 3) / 4, 64, 0, stream>>>(h2, asrc2, adst2, rowptr, srcs, b2, (float*)d_out, N);
}

// Round 2
// 620.136 us; speedup vs baseline: 1.1855x; 1.1855x over previous
//
#include <hip/hip_runtime.h>
#include <cstdint>
#include <cstddef>

#define NEG_SLOPE 0.2f

// ---------------------------------------------------------------------------
// N=100000, F_in=128, H=4, C1=32 (HC=128), C2=16, E=1600000 (+N self-loops).
// CSR-by-dst build (int atomics only), gather-side aggregation (no float
// atomics). GEMMs f32 vector (no fp32 MFMA on CDNA4).
// R1: agg kernels restructured — cooperative per-edge exp (1 per edge-head,
// not per-lane), shuffle broadcast, barrier-free; alpha1 fused into gemm1.
// ---------------------------------------------------------------------------

__device__ __forceinline__ int edge_at(const void* ei, long long idx, int is64) {
    if (is64) return (int)((const long long*)ei)[idx];
    return ((const int*)ei)[idx];
}

__global__ void detect_fmt_kernel(const void* ei, int* flag) {
    if (threadIdx.x == 0 && blockIdx.x == 0) {
        const unsigned* u = (const unsigned*)ei;
        int zc = 0;
        for (int i = 0; i < 128; ++i) zc += (u[2 * i + 1] == 0u);
        *flag = (zc >= 100) ? 1 : 0;
    }
}

// ---------------------------------------------------------------------------
// GEMM1: h1[N,128] = x[N,128] @ W1[128,128] + fused alpha_src/dst epilogue.
// BM=128, BN=128, BK=32, 256 threads, 8x8 register tile.
// ---------------------------------------------------------------------------
__global__ __launch_bounds__(256) void gemm1_kernel(
    const float* __restrict__ x, const float* __restrict__ W,
    const float* __restrict__ a_src, const float* __restrict__ a_dst,
    float* __restrict__ h1, float* __restrict__ asrc, float* __restrict__ adst,
    int N) {
    __shared__ float As[128][33];
    __shared__ float Bs[32][128];
    const int tid = threadIdx.x;
    const int tx = tid & 15, ty = tid >> 4;
    const int base = blockIdx.x * 128;

    float acc[8][8];
#pragma unroll
    for (int i = 0; i < 8; ++i)
#pragma unroll
        for (int j = 0; j < 8; ++j) acc[i][j] = 0.f;

    for (int kb = 0; kb < 128; kb += 32) {
        {   // stage x tile [128 rows][32 cols]
            const int r0 = tid >> 3;
            const int q  = tid & 7;
#pragma unroll
            for (int p = 0; p < 4; ++p) {
                int r = r0 + p * 32;
                int gr = base + r;
                float4 v = make_float4(0.f, 0.f, 0.f, 0.f);
                if (gr < N) v = *(const float4*)(x + (size_t)gr * 128 + kb + q * 4);
                As[r][q * 4 + 0] = v.x; As[r][q * 4 + 1] = v.y;
                As[r][q * 4 + 2] = v.z; As[r][q * 4 + 3] = v.w;
            }
        }
        {   // stage W tile [32 k][128 cols]
            const int k0 = tid >> 5;
            const int f  = tid & 31;
#pragma unroll
            for (int p = 0; p < 4; ++p) {
                int kk = k0 + p * 8;
                float4 v = *(const float4*)(W + (size_t)(kb + kk) * 128 + f * 4);
                *(float4*)&Bs[kk][f * 4] = v;
            }
        }
        __syncthreads();
#pragma unroll 4
        for (int kk = 0; kk < 32; ++kk) {
            float a[8];
#pragma unroll
            for (int i = 0; i < 8; ++i) a[i] = As[ty * 8 + i][kk];
            float4 b0 = *(const float4*)&Bs[kk][tx * 4];
            float4 b1 = *(const float4*)&Bs[kk][64 + tx * 4];
            float b[8] = {b0.x, b0.y, b0.z, b0.w, b1.x, b1.y, b1.z, b1.w};
#pragma unroll
            for (int i = 0; i < 8; ++i)
#pragma unroll
                for (int j = 0; j < 8; ++j)
                    acc[i][j] = fmaf(a[i], b[j], acc[i][j]);
        }
        __syncthreads();
    }

    // a_src/a_dst at this thread's 8 columns: tx*4+jj (head tx>>3) and
    // 64+tx*4+jj (head 2+(tx>>3))
    float asv[8], adv[8];
#pragma unroll
    for (int jj = 0; jj < 4; ++jj) {
        asv[jj]     = a_src[tx * 4 + jj];
        asv[4 + jj] = a_src[64 + tx * 4 + jj];
        adv[jj]     = a_dst[tx * 4 + jj];
        adv[4 + jj] = a_dst[64 + tx * 4 + jj];
    }

#pragma unroll
    for (int i = 0; i < 8; ++i) {
        int gr = base + ty * 8 + i;
        float p0s = 0.f, p1s = 0.f, p0d = 0.f, p1d = 0.f;
#pragma unroll
        for (int jj = 0; jj < 4; ++jj) {
            p0s = fmaf(acc[i][jj],     asv[jj],     p0s);
            p0d = fmaf(acc[i][jj],     adv[jj],     p0d);
            p1s = fmaf(acc[i][4 + jj], asv[4 + jj], p1s);
            p1d = fmaf(acc[i][4 + jj], adv[4 + jj], p1d);
        }
        // reduce across the 8-lane tx subgroup (lane bits 0..2)
#pragma unroll
        for (int off = 1; off < 8; off <<= 1) {
            p0s += __shfl_xor(p0s, off);
            p0d += __shfl_xor(p0d, off);
            p1s += __shfl_xor(p1s, off);
            p1d += __shfl_xor(p1d, off);
        }
        if (gr < N) {
            float4 o0 = make_float4(acc[i][0], acc[i][1], acc[i][2], acc[i][3]);
            float4 o1 = make_float4(acc[i][4], acc[i][5], acc[i][6], acc[i][7]);
            *(float4*)(h1 + (size_t)gr * 128 + tx * 4) = o0;
            *(float4*)(h1 + (size_t)gr * 128 + 64 + tx * 4) = o1;
            if ((tx & 7) == 0) {
                int hlo = tx >> 3;           // 0 or 1
                asrc[gr * 4 + hlo]     = p0s;
                adst[gr * 4 + hlo]     = p0d;
                asrc[gr * 4 + 2 + hlo] = p1s;
                adst[gr * 4 + 2 + hlo] = p1d;
            }
        }
    }
}

// ---------------------------------------------------------------------------
// CSR build
// ---------------------------------------------------------------------------
__global__ void deg_init_kernel(int* deg, int* cursor, int N) {
    int i = blockIdx.x * 256 + threadIdx.x;
    if (i < N) { deg[i] = 1; cursor[i] = 0; }
}

__global__ void hist_kernel(const void* ei, int* deg, int E, const int* flag) {
    int i = blockIdx.x * 256 + threadIdx.x;
    if (i < E) {
        int is64 = *flag;
        int d = edge_at(ei, (long long)E + i, is64);
        atomicAdd(&deg[d], 1);
    }
}

__global__ void reduce_kernel(const int* __restrict__ deg, int* bsums, int N) {
    __shared__ int s[256];
    int tid = threadIdx.x;
    int base = blockIdx.x * 1024 + tid * 4;
    int t = 0;
#pragma unroll
    for (int u = 0; u < 4; ++u) { int idx = base + u; if (idx < N) t += deg[idx]; }
    s[tid] = t;
    __syncthreads();
    for (int off = 128; off; off >>= 1) {
        if (tid < off) s[tid] += s[tid + off];
        __syncthreads();
    }
    if (tid == 0) bsums[blockIdx.x] = s[0];
}

__global__ void scan_bsums_kernel(int* bsums, int* rowptr, int nb, int N) {
    if (threadIdx.x == 0 && blockIdx.x == 0) {
        int run = 0;
        for (int b = 0; b < nb; ++b) { int t = bsums[b]; bsums[b] = run; run += t; }
        rowptr[N] = run;
    }
}

__global__ void scan_write_kernel(const int* __restrict__ deg,
                                  const int* __restrict__ bsums,
                                  int* __restrict__ rowptr, int N) {
    __shared__ int s[256];
    int tid = threadIdx.x;
    int base_i = blockIdx.x * 1024 + tid * 4;
    int v[4]; int t = 0;
#pragma unroll
    for (int u = 0; u < 4; ++u) {
        int idx = base_i + u;
        v[u] = (idx < N) ? deg[idx] : 0;
        t += v[u];
    }
    s[tid] = t;
    __syncthreads();
    for (int off = 1; off < 256; off <<= 1) {
        int tv = (tid >= off) ? s[tid - off] : 0;
        __syncthreads();
        s[tid] += tv;
        __syncthreads();
    }
    int excl = (tid == 0) ? 0 : s[tid - 1];
    int p = bsums[blockIdx.x] + excl;
#pragma unroll
    for (int u = 0; u < 4; ++u) {
        int idx = base_i + u;
        if (idx < N) rowptr[idx] = p;
        p += v[u];
    }
}

__global__ void scatter_kernel(const void* ei, const int* __restrict__ rowptr,
                               int* cursor, int* __restrict__ srcs,
                               int E, int ET, const int* flag) {
    int i = blockIdx.x * 256 + threadIdx.x;
    if (i < ET) {
        int is64 = *flag;
        int s, d;
        if (i < E) {
            s = edge_at(ei, i, is64);
            d = edge_at(ei, (long long)E + i, is64);
        } else {
            s = d = i - E;
        }
        int pos = rowptr[d] + atomicAdd(&cursor[d], 1);
        srcs[pos] = s;
    }
}

// ---------------------------------------------------------------------------
// Layer-1 aggregation: 128 threads = one dst node; thread = channel,
// head h = c>>5, lane l = c&31. Barrier-free: per-edge exp computed once per
// (edge, head) by lane l, broadcast via __shfl within the 32-lane head group.
// ---------------------------------------------------------------------------
__global__ __launch_bounds__(128) void agg1_kernel(
    const float* __restrict__ h1, const float* __restrict__ asrc,
    const float* __restrict__ adst, const int* __restrict__ rowptr,
    const int* __restrict__ srcs, const float* __restrict__ b1,
    float* __restrict__ g, int N) {
    int d = blockIdx.x;
    int tid = threadIdx.x;
    int h = tid >> 5, l = tid & 31;
    int start = rowptr[d], end = rowptr[d + 1];
    int deg = end - start;
    float ad = adst[d * 4 + h];

    // phase A: per-head max, lane-parallel (deg/32 iterations)
    float m = -1e30f;
    for (int j = start + l; j < end; j += 32) {
        float t = asrc[srcs[j] * 4 + h] + ad;
        t = (t > 0.f) ? t : NEG_SLOPE * t;
        m = fmaxf(m, t);
    }
#pragma unroll
    for (int off = 16; off; off >>= 1) m = fmaxf(m, __shfl_xor(m, off, 32));

    // phase B: chunks of 32 edges; lane l computes w for edge l of chunk
    float acc = 0.f, lsum = 0.f;
    for (int cb = 0; cb < deg; cb += 32) {
        int cl = min(32, deg - cb);
        float wv = 0.f; int sv = 0;
        if (l < cl) {
            sv = srcs[start + cb + l];
            float t = asrc[sv * 4 + h] + ad;
            t = (t > 0.f) ? t : NEG_SLOPE * t;
            wv = __expf(t - m);
        }
        for (int e = 0; e < cl; ++e) {
            float w = __shfl(wv, e, 32);
            int s = __shfl(sv, e, 32);
            lsum += w;
            acc = fmaf(w, h1[(size_t)s * 128 + tid], acc);
        }
    }
    float r = acc / lsum + b1[tid];
    g[(size_t)d * 128 + tid] = (r > 0.f) ? r : expm1f(r);
}

// ---------------------------------------------------------------------------
// GEMM2 + alpha2: h2[N,16] = g[N,128] @ W2[128,16]
// ---------------------------------------------------------------------------
__global__ __launch_bounds__(256) void gemm2_kernel(
    const float* __restrict__ g, const float* __restrict__ W2,
    const float* __restrict__ a_src2, const float* __restrict__ a_dst2,
    float* __restrict__ h2, float* __restrict__ asrc2, float* __restrict__ adst2,
    int N) {
    __shared__ float W2s[128 * 16];
    __shared__ float gs[16][132];
    int tid = threadIdx.x;
#pragma unroll
    for (int u = 0; u < 8; ++u) W2s[u * 256 + tid] = W2[u * 256 + tid];
    int base = blockIdx.x * 16;
#pragma unroll
    for (int p = 0; p < 2; ++p) {
        int q = tid + p * 256;
        int r = q >> 5, c4 = q & 31;
        int gr = base + r;
        float4 v = make_float4(0.f, 0.f, 0.f, 0.f);
        if (gr < N) v = *(const float4*)(g + (size_t)gr * 128 + c4 * 4);
        *(float4*)&gs[r][c4 * 4] = v;
    }
    __syncthreads();
    int ln = tid >> 4, c = tid & 15;
    int n = base + ln;
    float acc = 0.f;
#pragma unroll 8
    for (int k = 0; k < 128; ++k)
        acc = fmaf(gs[ln][k], W2s[k * 16 + c], acc);
    float s1 = acc * a_src2[c];
    float s2 = acc * a_dst2[c];
#pragma unroll
    for (int off = 8; off; off >>= 1) {
        s1 += __shfl_xor(s1, off, 16);
        s2 += __shfl_xor(s2, off, 16);
    }
    if (n < N) {
        h2[(size_t)n * 16 + c] = acc;
        if (c == 0) { asrc2[n] = s1; adst2[n] = s2; }
    }
}

// Layer-2 aggregation: 64 threads = 4 nodes x 16 channels, barrier-free,
// per-edge exp computed once by lane c, broadcast via 16-wide shuffles.
__global__ __launch_bounds__(64) void agg2_kernel(
    const float* __restrict__ h2, const float* __restrict__ asrc2,
    const float* __restrict__ adst2, const int* __restrict__ rowptr,
    const int* __restrict__ srcs, const float* __restrict__ b2,
    float* __restrict__ out, int N) {
    int tid = threadIdx.x;
    int d = blockIdx.x * 4 + (tid >> 4);
    int c = tid & 15;
    if (d >= N) return;
    int start = rowptr[d], end = rowptr[d + 1];
    int deg = end - start;
    float ad = adst2[d];

    float m = -1e30f;
    for (int j = start + c; j < end; j += 16) {
        float t = asrc2[srcs[j]] + ad;
        t = (t > 0.f) ? t : NEG_SLOPE * t;
        m = fmaxf(m, t);
    }
#pragma unroll
    for (int off = 8; off; off >>= 1) m = fmaxf(m, __shfl_xor(m, off, 16));

    float acc = 0.f, lsum = 0.f;
    for (int cb = 0; cb < deg; cb += 16) {
        int cl = min(16, deg - cb);
        float wv = 0.f; int sv = 0;
        if (c < cl) {
            sv = srcs[start + cb + c];
            float t = asrc2[sv] + ad;
            t = (t > 0.f) ? t : NEG_SLOPE * t;
            wv = __expf(t - m);
        }
        for (int e = 0; e < cl; ++e) {
            float w = __shfl(wv, e, 16);
            int s = __shfl(sv, e, 16);
            lsum += w;
            acc = fmaf(w, h2[(size_t)s * 16 + c], acc);
        }
    }
    out[(size_t)d * 16 + c] = acc / lsum + b2[c];
}

// ---------------------------------------------------------------------------
extern "C" void kernel_launch(void* const* d_in, const int* in_sizes, int n_in,
                              void* d_out, int out_size, void* d_ws, size_t ws_size,
                              hipStream_t stream) {
    const float* x      = (const float*)d_in[0];
    const void*  ei     = d_in[1];
    const float* W1     = (const float*)d_in[2];
    const float* a_src1 = (const float*)d_in[3];
    const float* a_dst1 = (const float*)d_in[4];
    const float* b1     = (const float*)d_in[5];
    const float* W2     = (const float*)d_in[6];
    const float* a_src2 = (const float*)d_in[7];
    const float* a_dst2 = (const float*)d_in[8];
    const float* b2     = (const float*)d_in[9];

    const int N  = in_sizes[0] / 128;   // 100000
    const int E  = in_sizes[1] / 2;     // 1600000
    const int ET = E + N;

    char* w = (char*)d_ws;
    size_t off = 0;
    auto alloc = [&](size_t bytes) -> char* {
        char* p = w + off;
        off = (off + bytes + 255) & ~(size_t)255;
        return p;
    };
    float* h1     = (float*)alloc((size_t)N * 128 * 4);
    float* g      = (float*)alloc((size_t)N * 128 * 4);
    float* asrc1  = (float*)alloc((size_t)N * 4 * 4);
    float* adst1  = (float*)alloc((size_t)N * 4 * 4);
    int*   deg    = (int*)alloc((size_t)N * 4);
    int*   cursor = (int*)alloc((size_t)N * 4);
    int*   rowptr = (int*)alloc((size_t)(N + 1) * 4);
    int*   srcs   = (int*)alloc((size_t)ET * 4);
    int*   bsums  = (int*)alloc(4096);
    int*   flag   = (int*)alloc(256);
    float* h2    = h1;                       // h1 dead after agg1
    float* asrc2 = h1 + (size_t)N * 16;
    float* adst2 = asrc2 + N;

    const int nb = (N + 1023) / 1024;

    detect_fmt_kernel<<<1, 1, 0, stream>>>(ei, flag);
    gemm1_kernel<<<(N + 127) / 128, 256, 0, stream>>>(x, W1, a_src1, a_dst1,
                                                      h1, asrc1, adst1, N);
    deg_init_kernel<<<(N + 255) / 256, 256, 0, stream>>>(deg, cursor, N);
    hist_kernel<<<(E + 255) / 256, 256, 0, stream>>>(ei, deg, E, flag);
    reduce_kernel<<<nb, 256, 0, stream>>>(deg, bsums, N);
    scan_bsums_kernel<<<1, 1, 0, stream>>>(bsums, rowptr, nb, N);
    scan_write_kernel<<<nb, 256, 0, stream>>>(deg, bsums, rowptr, N);
    scatter_kernel<<<(ET + 255) / 256, 256, 0, stream>>>(ei, rowptr, cursor, srcs, E, ET, flag);
    agg1_kernel<<<N, 128, 0, stream>>>(h1, asrc1, adst1, rowptr, srcs, b1, g, N);
    gemm2_kernel<<<(N + 15) / 16, 256, 0, stream>>>(g, W2, a_src2, a_dst2, h2, asrc2, adst2, N);
    agg2_kernel<<<(N + 3) / 4, 64, 0, stream>>>(h2, asrc2, adst2, rowptr, srcs, b2, (float*)d_out, N);
}

// Round 8
// 549.769 us; speedup vs baseline: 1.3373x; 1.1280x over previous
//
#include <hip/hip_runtime.h>
#include <cstdint>
#include <cstddef>

#define NEG_SLOPE 0.2f

// ---------------------------------------------------------------------------
// N=100000, F_in=128, H=4, C1=32 (HC=128), C2=16, E=1600000 (+N self-loops).
// CSR-by-dst build (int atomics only), gather-side aggregation (no float
// atomics). GEMMs f32 vector (no fp32 MFMA on CDNA4).
// R1: cooperative per-edge exp + shuffle broadcast; alpha1 fused into gemm1.
// R2: 8-way MLP unroll in agg1/agg2 (latency-bound gather fix), 256-thread
//     agg2 blocks, parallel block-sum scan, gemm1 transposed-A ds_read_b128.
// R3: resubmit (GPUAcquisitionTimeout).
// R4: FIX agg2 grid bug from R2 ((N+255)/256 -> (N+15)/16).
// R5: resubmit of R4 (GPUAcquisitionTimeout); source re-audit clean.
// R6: resubmit of R4 (GPUAcquisitionTimeout x3).
// R7: resubmit of R4 (GPUAcquisitionTimeout x4). Discipline: no speculative
//     edits while the queued optimization set is unmeasured; a correctness
//     bug would burn the next successful bench slot.
// ---------------------------------------------------------------------------

__device__ __forceinline__ int edge_at(const void* ei, long long idx, int is64) {
    if (is64) return (int)((const long long*)ei)[idx];
    return ((const int*)ei)[idx];
}

__global__ void detect_fmt_kernel(const void* ei, int* flag) {
    if (threadIdx.x == 0 && blockIdx.x == 0) {
        const unsigned* u = (const unsigned*)ei;
        int zc = 0;
        for (int i = 0; i < 128; ++i) zc += (u[2 * i + 1] == 0u);
        *flag = (zc >= 100) ? 1 : 0;
    }
}

// ---------------------------------------------------------------------------
// GEMM1: h1[N,128] = x[N,128] @ W1[128,128] + fused alpha_src/dst epilogue.
// BM=128, BN=128, BK=32, 256 threads, 8x8 register tile. A staged TRANSPOSED
// (As2[k][row], pad 132 words = 16B-aligned rows) so a-frag = 2x ds_read_b128.
// ---------------------------------------------------------------------------
__global__ __launch_bounds__(256) void gemm1_kernel(
    const float* __restrict__ x, const float* __restrict__ W,
    const float* __restrict__ a_src, const float* __restrict__ a_dst,
    float* __restrict__ h1, float* __restrict__ asrc, float* __restrict__ adst,
    int N) {
    __shared__ float As2[32][132];
    __shared__ float Bs[32][128];
    const int tid = threadIdx.x;
    const int tx = tid & 15, ty = tid >> 4;
    const int base = blockIdx.x * 128;

    float acc[8][8];
#pragma unroll
    for (int i = 0; i < 8; ++i)
#pragma unroll
        for (int j = 0; j < 8; ++j) acc[i][j] = 0.f;

    for (int kb = 0; kb < 128; kb += 32) {
        {   // stage x tile transposed: As2[k][row]
            const int r0 = tid >> 3;   // 0..31
            const int q  = tid & 7;    // k-quad
#pragma unroll
            for (int p = 0; p < 4; ++p) {
                int r = r0 + p * 32;
                int gr = base + r;
                float4 v = make_float4(0.f, 0.f, 0.f, 0.f);
                if (gr < N) v = *(const float4*)(x + (size_t)gr * 128 + kb + q * 4);
                As2[q * 4 + 0][r] = v.x; As2[q * 4 + 1][r] = v.y;
                As2[q * 4 + 2][r] = v.z; As2[q * 4 + 3][r] = v.w;
            }
        }
        {   // stage W tile [32 k][128 cols]
            const int k0 = tid >> 5;
            const int f  = tid & 31;
#pragma unroll
            for (int p = 0; p < 4; ++p) {
                int kk = k0 + p * 8;
                float4 v = *(const float4*)(W + (size_t)(kb + kk) * 128 + f * 4);
                *(float4*)&Bs[kk][f * 4] = v;
            }
        }
        __syncthreads();
#pragma unroll 4
        for (int kk = 0; kk < 32; ++kk) {
            float4 a0 = *(const float4*)&As2[kk][ty * 8];
            float4 a1 = *(const float4*)&As2[kk][ty * 8 + 4];
            float a[8] = {a0.x, a0.y, a0.z, a0.w, a1.x, a1.y, a1.z, a1.w};
            float4 b0 = *(const float4*)&Bs[kk][tx * 4];
            float4 b1 = *(const float4*)&Bs[kk][64 + tx * 4];
            float b[8] = {b0.x, b0.y, b0.z, b0.w, b1.x, b1.y, b1.z, b1.w};
#pragma unroll
            for (int i = 0; i < 8; ++i)
#pragma unroll
                for (int j = 0; j < 8; ++j)
                    acc[i][j] = fmaf(a[i], b[j], acc[i][j]);
        }
        __syncthreads();
    }

    float asv[8], adv[8];
#pragma unroll
    for (int jj = 0; jj < 4; ++jj) {
        asv[jj]     = a_src[tx * 4 + jj];
        asv[4 + jj] = a_src[64 + tx * 4 + jj];
        adv[jj]     = a_dst[tx * 4 + jj];
        adv[4 + jj] = a_dst[64 + tx * 4 + jj];
    }

#pragma unroll
    for (int i = 0; i < 8; ++i) {
        int gr = base + ty * 8 + i;
        float p0s = 0.f, p1s = 0.f, p0d = 0.f, p1d = 0.f;
#pragma unroll
        for (int jj = 0; jj < 4; ++jj) {
            p0s = fmaf(acc[i][jj],     asv[jj],     p0s);
            p0d = fmaf(acc[i][jj],     adv[jj],     p0d);
            p1s = fmaf(acc[i][4 + jj], asv[4 + jj], p1s);
            p1d = fmaf(acc[i][4 + jj], adv[4 + jj], p1d);
        }
#pragma unroll
        for (int off = 1; off < 8; off <<= 1) {
            p0s += __shfl_xor(p0s, off);
            p0d += __shfl_xor(p0d, off);
            p1s += __shfl_xor(p1s, off);
            p1d += __shfl_xor(p1d, off);
        }
        if (gr < N) {
            float4 o0 = make_float4(acc[i][0], acc[i][1], acc[i][2], acc[i][3]);
            float4 o1 = make_float4(acc[i][4], acc[i][5], acc[i][6], acc[i][7]);
            *(float4*)(h1 + (size_t)gr * 128 + tx * 4) = o0;
            *(float4*)(h1 + (size_t)gr * 128 + 64 + tx * 4) = o1;
            if ((tx & 7) == 0) {
                int hlo = tx >> 3;
                asrc[gr * 4 + hlo]     = p0s;
                adst[gr * 4 + hlo]     = p0d;
                asrc[gr * 4 + 2 + hlo] = p1s;
                adst[gr * 4 + 2 + hlo] = p1d;
            }
        }
    }
}

// ---------------------------------------------------------------------------
// CSR build
// ---------------------------------------------------------------------------
__global__ void deg_init_kernel(int* deg, int* cursor, int N) {
    int i = blockIdx.x * 256 + threadIdx.x;
    if (i < N) { deg[i] = 1; cursor[i] = 0; }
}

__global__ void hist_kernel(const void* ei, int* deg, int E, const int* flag) {
    int i = blockIdx.x * 256 + threadIdx.x;
    if (i < E) {
        int is64 = *flag;
        int d = edge_at(ei, (long long)E + i, is64);
        atomicAdd(&deg[d], 1);
    }
}

__global__ void reduce_kernel(const int* __restrict__ deg, int* bsums, int N) {
    __shared__ int s[256];
    int tid = threadIdx.x;
    int base = blockIdx.x * 1024 + tid * 4;
    int t = 0;
#pragma unroll
    for (int u = 0; u < 4; ++u) { int idx = base + u; if (idx < N) t += deg[idx]; }
    s[tid] = t;
    __syncthreads();
    for (int off = 128; off; off >>= 1) {
        if (tid < off) s[tid] += s[tid + off];
        __syncthreads();
    }
    if (tid == 0) bsums[blockIdx.x] = s[0];
}

// parallel scan of block sums (single 128-thread block, tiles of 128)
__global__ void scan_bsums_kernel(int* bsums, int* rowptr, int nb, int N) {
    __shared__ int s[128];
    __shared__ int carry;
    int tid = threadIdx.x;
    if (tid == 0) carry = 0;
    __syncthreads();
    for (int base = 0; base < nb; base += 128) {
        int idx = base + tid;
        int v = (idx < nb) ? bsums[idx] : 0;
        s[tid] = v;
        __syncthreads();
        for (int off = 1; off < 128; off <<= 1) {
            int t = (tid >= off) ? s[tid - off] : 0;
            __syncthreads();
            s[tid] += t;
            __syncthreads();
        }
        int excl = carry + ((tid == 0) ? 0 : s[tid - 1]);
        if (idx < nb) bsums[idx] = excl;
        __syncthreads();
        if (tid == 0) carry += s[127];
        __syncthreads();
    }
    if (tid == 0) rowptr[N] = carry;
}

__global__ void scan_write_kernel(const int* __restrict__ deg,
                                  const int* __restrict__ bsums,
                                  int* __restrict__ rowptr, int N) {
    __shared__ int s[256];
    int tid = threadIdx.x;
    int base_i = blockIdx.x * 1024 + tid * 4;
    int v[4]; int t = 0;
#pragma unroll
    for (int u = 0; u < 4; ++u) {
        int idx = base_i + u;
        v[u] = (idx < N) ? deg[idx] : 0;
        t += v[u];
    }
    s[tid] = t;
    __syncthreads();
    for (int off = 1; off < 256; off <<= 1) {
        int tv = (tid >= off) ? s[tid - off] : 0;
        __syncthreads();
        s[tid] += tv;
        __syncthreads();
    }
    int excl = (tid == 0) ? 0 : s[tid - 1];
    int p = bsums[blockIdx.x] + excl;
#pragma unroll
    for (int u = 0; u < 4; ++u) {
        int idx = base_i + u;
        if (idx < N) rowptr[idx] = p;
        p += v[u];
    }
}

__global__ void scatter_kernel(const void* ei, const int* __restrict__ rowptr,
                               int* cursor, int* __restrict__ srcs,
                               int E, int ET, const int* flag) {
    int i = blockIdx.x * 256 + threadIdx.x;
    if (i < ET) {
        int is64 = *flag;
        int s, d;
        if (i < E) {
            s = edge_at(ei, i, is64);
            d = edge_at(ei, (long long)E + i, is64);
        } else {
            s = d = i - E;
        }
        int pos = rowptr[d] + atomicAdd(&cursor[d], 1);
        srcs[pos] = s;
    }
}

// ---------------------------------------------------------------------------
// Layer-1 aggregation: 128 threads = one dst node; thread = channel,
// head h = c>>5, lane l = c&31. Cooperative exp (one per edge-head), shuffle
// broadcast, 8-way unrolled gather for memory-level parallelism.
// ---------------------------------------------------------------------------
__global__ __launch_bounds__(128) void agg1_kernel(
    const float* __restrict__ h1, const float* __restrict__ asrc,
    const float* __restrict__ adst, const int* __restrict__ rowptr,
    const int* __restrict__ srcs, const float* __restrict__ b1,
    float* __restrict__ g, int N) {
    int d = blockIdx.x;
    int tid = threadIdx.x;
    int h = tid >> 5, l = tid & 31;
    int start = rowptr[d], end = rowptr[d + 1];
    int deg = end - start;
    float ad = adst[d * 4 + h];

    // phase A: per-head max, lane-parallel
    float m = -1e30f;
    for (int j = start + l; j < end; j += 32) {
        float t = asrc[srcs[j] * 4 + h] + ad;
        t = (t > 0.f) ? t : NEG_SLOPE * t;
        m = fmaxf(m, t);
    }
#pragma unroll
    for (int off = 16; off; off >>= 1) m = fmaxf(m, __shfl_xor(m, off, 32));

    // phase B: chunks of 32 edges; lane l computes w for edge l of chunk;
    // 8 independent accumulators keep 8 h1-row loads in flight.
    float a0 = 0.f, a1 = 0.f, a2 = 0.f, a3 = 0.f;
    float a4 = 0.f, a5 = 0.f, a6 = 0.f, a7 = 0.f;
    float lsum = 0.f;
    const float* h1c = h1 + tid;
    for (int cb = 0; cb < deg; cb += 32) {
        int cl = min(32, deg - cb);
        float wv = 0.f; int sv = 0;
        if (l < cl) {
            sv = srcs[start + cb + l];
            float t = asrc[sv * 4 + h] + ad;
            t = (t > 0.f) ? t : NEG_SLOPE * t;
            wv = __expf(t - m);
        }
        lsum += wv;   // deferred: reduced across lanes after the loop
        int e = 0;
        for (; e + 8 <= cl; e += 8) {
            int  s0 = __shfl(sv, e + 0, 32), s1 = __shfl(sv, e + 1, 32);
            int  s2 = __shfl(sv, e + 2, 32), s3 = __shfl(sv, e + 3, 32);
            int  s4 = __shfl(sv, e + 4, 32), s5 = __shfl(sv, e + 5, 32);
            int  s6 = __shfl(sv, e + 6, 32), s7 = __shfl(sv, e + 7, 32);
            float w0 = __shfl(wv, e + 0, 32), w1 = __shfl(wv, e + 1, 32);
            float w2 = __shfl(wv, e + 2, 32), w3 = __shfl(wv, e + 3, 32);
            float w4 = __shfl(wv, e + 4, 32), w5 = __shfl(wv, e + 5, 32);
            float w6 = __shfl(wv, e + 6, 32), w7 = __shfl(wv, e + 7, 32);
            a0 = fmaf(w0, h1c[(size_t)s0 * 128], a0);
            a1 = fmaf(w1, h1c[(size_t)s1 * 128], a1);
            a2 = fmaf(w2, h1c[(size_t)s2 * 128], a2);
            a3 = fmaf(w3, h1c[(size_t)s3 * 128], a3);
            a4 = fmaf(w4, h1c[(size_t)s4 * 128], a4);
            a5 = fmaf(w5, h1c[(size_t)s5 * 128], a5);
            a6 = fmaf(w6, h1c[(size_t)s6 * 128], a6);
            a7 = fmaf(w7, h1c[(size_t)s7 * 128], a7);
        }
        for (; e < cl; ++e) {
            int s = __shfl(sv, e, 32);
            float w = __shfl(wv, e, 32);
            a0 = fmaf(w, h1c[(size_t)s * 128], a0);
        }
    }
#pragma unroll
    for (int off = 16; off; off >>= 1) lsum += __shfl_xor(lsum, off, 32);
    float acc = ((a0 + a1) + (a2 + a3)) + ((a4 + a5) + (a6 + a7));
    float r = acc / lsum + b1[tid];
    g[(size_t)d * 128 + tid] = (r > 0.f) ? r : expm1f(r);
}

// ---------------------------------------------------------------------------
// GEMM2 + alpha2: h2[N,16] = g[N,128] @ W2[128,16]
// ---------------------------------------------------------------------------
__global__ __launch_bounds__(256) void gemm2_kernel(
    const float* __restrict__ g, const float* __restrict__ W2,
    const float* __restrict__ a_src2, const float* __restrict__ a_dst2,
    float* __restrict__ h2, float* __restrict__ asrc2, float* __restrict__ adst2,
    int N) {
    __shared__ float W2s[128 * 16];
    __shared__ float gs[16][132];
    int tid = threadIdx.x;
#pragma unroll
    for (int u = 0; u < 8; ++u) W2s[u * 256 + tid] = W2[u * 256 + tid];
    int base = blockIdx.x * 16;
#pragma unroll
    for (int p = 0; p < 2; ++p) {
        int q = tid + p * 256;
        int r = q >> 5, c4 = q & 31;
        int gr = base + r;
        float4 v = make_float4(0.f, 0.f, 0.f, 0.f);
        if (gr < N) v = *(const float4*)(g + (size_t)gr * 128 + c4 * 4);
        *(float4*)&gs[r][c4 * 4] = v;
    }
    __syncthreads();
    int ln = tid >> 4, c = tid & 15;
    int n = base + ln;
    float acc = 0.f;
#pragma unroll 8
    for (int k = 0; k < 128; ++k)
        acc = fmaf(gs[ln][k], W2s[k * 16 + c], acc);
    float s1 = acc * a_src2[c];
    float s2 = acc * a_dst2[c];
#pragma unroll
    for (int off = 8; off; off >>= 1) {
        s1 += __shfl_xor(s1, off, 16);
        s2 += __shfl_xor(s2, off, 16);
    }
    if (n < N) {
        h2[(size_t)n * 16 + c] = acc;
        if (c == 0) { asrc2[n] = s1; adst2[n] = s2; }
    }
}

// Layer-2 aggregation: 256 threads = 16 nodes x 16 channels, cooperative exp,
// 8-way unrolled gather.
__global__ __launch_bounds__(256) void agg2_kernel(
    const float* __restrict__ h2, const float* __restrict__ asrc2,
    const float* __restrict__ adst2, const int* __restrict__ rowptr,
    const int* __restrict__ srcs, const float* __restrict__ b2,
    float* __restrict__ out, int N) {
    int tid = threadIdx.x;
    int d = blockIdx.x * 16 + (tid >> 4);
    int c = tid & 15;
    if (d >= N) return;
    int start = rowptr[d], end = rowptr[d + 1];
    int deg = end - start;
    float ad = adst2[d];

    float m = -1e30f;
    for (int j = start + c; j < end; j += 16) {
        float t = asrc2[srcs[j]] + ad;
        t = (t > 0.f) ? t : NEG_SLOPE * t;
        m = fmaxf(m, t);
    }
#pragma unroll
    for (int off = 8; off; off >>= 1) m = fmaxf(m, __shfl_xor(m, off, 16));

    float a0 = 0.f, a1 = 0.f, a2 = 0.f, a3 = 0.f;
    float a4 = 0.f, a5 = 0.f, a6 = 0.f, a7 = 0.f;
    float lsum = 0.f;
    const float* h2c = h2 + c;
    for (int cb = 0; cb < deg; cb += 16) {
        int cl = min(16, deg - cb);
        float wv = 0.f; int sv = 0;
        if (c < cl) {
            sv = srcs[start + cb + c];
            float t = asrc2[sv] + ad;
            t = (t > 0.f) ? t : NEG_SLOPE * t;
            wv = __expf(t - m);
        }
        lsum += wv;
        int e = 0;
        for (; e + 8 <= cl; e += 8) {
            int  s0 = __shfl(sv, e + 0, 16), s1 = __shfl(sv, e + 1, 16);
            int  s2 = __shfl(sv, e + 2, 16), s3 = __shfl(sv, e + 3, 16);
            int  s4 = __shfl(sv, e + 4, 16), s5 = __shfl(sv, e + 5, 16);
            int  s6 = __shfl(sv, e + 6, 16), s7 = __shfl(sv, e + 7, 16);
            float w0 = __shfl(wv, e + 0, 16), w1 = __shfl(wv, e + 1, 16);
            float w2 = __shfl(wv, e + 2, 16), w3 = __shfl(wv, e + 3, 16);
            float w4 = __shfl(wv, e + 4, 16), w5 = __shfl(wv, e + 5, 16);
            float w6 = __shfl(wv, e + 6, 16), w7 = __shfl(wv, e + 7, 16);
            a0 = fmaf(w0, h2c[(size_t)s0 * 16], a0);
            a1 = fmaf(w1, h2c[(size_t)s1 * 16], a1);
            a2 = fmaf(w2, h2c[(size_t)s2 * 16], a2);
            a3 = fmaf(w3, h2c[(size_t)s3 * 16], a3);
            a4 = fmaf(w4, h2c[(size_t)s4 * 16], a4);
            a5 = fmaf(w5, h2c[(size_t)s5 * 16], a5);
            a6 = fmaf(w6, h2c[(size_t)s6 * 16], a6);
            a7 = fmaf(w7, h2c[(size_t)s7 * 16], a7);
        }
        for (; e < cl; ++e) {
            int s = __shfl(sv, e, 16);
            float w = __shfl(wv, e, 16);
            a0 = fmaf(w, h2c[(size_t)s * 16], a0);
        }
    }
#pragma unroll
    for (int off = 8; off; off >>= 1) lsum += __shfl_xor(lsum, off, 16);
    float acc = ((a0 + a1) + (a2 + a3)) + ((a4 + a5) + (a6 + a7));
    out[(size_t)d * 16 + c] = acc / lsum + b2[c];
}

// ---------------------------------------------------------------------------
extern "C" void kernel_launch(void* const* d_in, const int* in_sizes, int n_in,
                              void* d_out, int out_size, void* d_ws, size_t ws_size,
                              hipStream_t stream) {
    const float* x      = (const float*)d_in[0];
    const void*  ei     = d_in[1];
    const float* W1     = (const float*)d_in[2];
    const float* a_src1 = (const float*)d_in[3];
    const float* a_dst1 = (const float*)d_in[4];
    const float* b1     = (const float*)d_in[5];
    const float* W2     = (const float*)d_in[6];
    const float* a_src2 = (const float*)d_in[7];
    const float* a_dst2 = (const float*)d_in[8];
    const float* b2     = (const float*)d_in[9];

    const int N  = in_sizes[0] / 128;   // 100000
    const int E  = in_sizes[1] / 2;     // 1600000
    const int ET = E + N;

    char* w = (char*)d_ws;
    size_t off = 0;
    auto alloc = [&](size_t bytes) -> char* {
        char* p = w + off;
        off = (off + bytes + 255) & ~(size_t)255;
        return p;
    };
    float* h1     = (float*)alloc((size_t)N * 128 * 4);
    float* g      = (float*)alloc((size_t)N * 128 * 4);
    float* asrc1  = (float*)alloc((size_t)N * 4 * 4);
    float* adst1  = (float*)alloc((size_t)N * 4 * 4);
    int*   deg    = (int*)alloc((size_t)N * 4);
    int*   cursor = (int*)alloc((size_t)N * 4);
    int*   rowptr = (int*)alloc((size_t)(N + 1) * 4);
    int*   srcs   = (int*)alloc((size_t)ET * 4);
    int*   bsums  = (int*)alloc(4096);
    int*   flag   = (int*)alloc(256);
    float* h2    = h1;                       // h1 dead after agg1
    float* asrc2 = h1 + (size_t)N * 16;
    float* adst2 = asrc2 + N;

    const int nb = (N + 1023) / 1024;

    detect_fmt_kernel<<<1, 1, 0, stream>>>(ei, flag);
    gemm1_kernel<<<(N + 127) / 128, 256, 0, stream>>>(x, W1, a_src1, a_dst1,
                                                      h1, asrc1, adst1, N);
    deg_init_kernel<<<(N + 255) / 256, 256, 0, stream>>>(deg, cursor, N);
    hist_kernel<<<(E + 255) / 256, 256, 0, stream>>>(ei, deg, E, flag);
    reduce_kernel<<<nb, 256, 0, stream>>>(deg, bsums, N);
    scan_bsums_kernel<<<1, 128, 0, stream>>>(bsums, rowptr, nb, N);
    scan_write_kernel<<<nb, 256, 0, stream>>>(deg, bsums, rowptr, N);
    scatter_kernel<<<(ET + 255) / 256, 256, 0, stream>>>(ei, rowptr, cursor, srcs, E, ET, flag);
    agg1_kernel<<<N, 128, 0, stream>>>(h1, asrc1, adst1, rowptr, srcs, b1, g, N);
    gemm2_kernel<<<(N + 15) / 16, 256, 0, stream>>>(g, W2, a_src2, a_dst2, h2, asrc2, adst2, N);
    agg2_kernel<<<(N + 15) / 16, 256, 0, stream>>>(h2, asrc2, adst2, rowptr, srcs, b2, (float*)d_out, N);
}

// Round 9
// 542.300 us; speedup vs baseline: 1.3557x; 1.0138x over previous
//
#include <hip/hip_runtime.h>
#include <cstdint>
#include <cstddef>

#define NEG_SLOPE 0.2f

// ---------------------------------------------------------------------------
// N=100000, F_in=128, H=4, C1=32 (HC=128), C2=16, E=1600000 (+N self-loops).
// CSR-by-dst build (int atomics only), gather-side aggregation (no float
// atomics). GEMMs f32 vector (no fp32 MFMA on CDNA4).
// R1: cooperative per-edge exp + shuffle broadcast; alpha1 fused into gemm1.
// R2: 8-way MLP unroll in agg1/agg2, 256-thread agg2, parallel scan,
//     gemm1 transposed-A. R4: agg2 grid fix. Measured R8: 549.8 us total,
//     agg1 147.8 us (DS/bpermute-pipe bound: 2 bpermutes/edge/wave).
// R9: replace shuffle broadcast with packed (w,s) LDS stage + uniform
//     ds_read_b64 broadcast -> 1 DS op/edge/wave (was 2). Same in agg2.
// ---------------------------------------------------------------------------

__device__ __forceinline__ int edge_at(const void* ei, long long idx, int is64) {
    if (is64) return (int)((const long long*)ei)[idx];
    return ((const int*)ei)[idx];
}

__global__ void detect_fmt_kernel(const void* ei, int* flag) {
    if (threadIdx.x == 0 && blockIdx.x == 0) {
        const unsigned* u = (const unsigned*)ei;
        int zc = 0;
        for (int i = 0; i < 128; ++i) zc += (u[2 * i + 1] == 0u);
        *flag = (zc >= 100) ? 1 : 0;
    }
}

// ---------------------------------------------------------------------------
// GEMM1: h1[N,128] = x[N,128] @ W1[128,128] + fused alpha_src/dst epilogue.
// ---------------------------------------------------------------------------
__global__ __launch_bounds__(256) void gemm1_kernel(
    const float* __restrict__ x, const float* __restrict__ W,
    const float* __restrict__ a_src, const float* __restrict__ a_dst,
    float* __restrict__ h1, float* __restrict__ asrc, float* __restrict__ adst,
    int N) {
    __shared__ float As2[32][132];
    __shared__ float Bs[32][128];
    const int tid = threadIdx.x;
    const int tx = tid & 15, ty = tid >> 4;
    const int base = blockIdx.x * 128;

    float acc[8][8];
#pragma unroll
    for (int i = 0; i < 8; ++i)
#pragma unroll
        for (int j = 0; j < 8; ++j) acc[i][j] = 0.f;

    for (int kb = 0; kb < 128; kb += 32) {
        {   // stage x tile transposed: As2[k][row]
            const int r0 = tid >> 3;   // 0..31
            const int q  = tid & 7;    // k-quad
#pragma unroll
            for (int p = 0; p < 4; ++p) {
                int r = r0 + p * 32;
                int gr = base + r;
                float4 v = make_float4(0.f, 0.f, 0.f, 0.f);
                if (gr < N) v = *(const float4*)(x + (size_t)gr * 128 + kb + q * 4);
                As2[q * 4 + 0][r] = v.x; As2[q * 4 + 1][r] = v.y;
                As2[q * 4 + 2][r] = v.z; As2[q * 4 + 3][r] = v.w;
            }
        }
        {   // stage W tile [32 k][128 cols]
            const int k0 = tid >> 5;
            const int f  = tid & 31;
#pragma unroll
            for (int p = 0; p < 4; ++p) {
                int kk = k0 + p * 8;
                float4 v = *(const float4*)(W + (size_t)(kb + kk) * 128 + f * 4);
                *(float4*)&Bs[kk][f * 4] = v;
            }
        }
        __syncthreads();
#pragma unroll 4
        for (int kk = 0; kk < 32; ++kk) {
            float4 a0 = *(const float4*)&As2[kk][ty * 8];
            float4 a1 = *(const float4*)&As2[kk][ty * 8 + 4];
            float a[8] = {a0.x, a0.y, a0.z, a0.w, a1.x, a1.y, a1.z, a1.w};
            float4 b0 = *(const float4*)&Bs[kk][tx * 4];
            float4 b1 = *(const float4*)&Bs[kk][64 + tx * 4];
            float b[8] = {b0.x, b0.y, b0.z, b0.w, b1.x, b1.y, b1.z, b1.w};
#pragma unroll
            for (int i = 0; i < 8; ++i)
#pragma unroll
                for (int j = 0; j < 8; ++j)
                    acc[i][j] = fmaf(a[i], b[j], acc[i][j]);
        }
        __syncthreads();
    }

    float asv[8], adv[8];
#pragma unroll
    for (int jj = 0; jj < 4; ++jj) {
        asv[jj]     = a_src[tx * 4 + jj];
        asv[4 + jj] = a_src[64 + tx * 4 + jj];
        adv[jj]     = a_dst[tx * 4 + jj];
        adv[4 + jj] = a_dst[64 + tx * 4 + jj];
    }

#pragma unroll
    for (int i = 0; i < 8; ++i) {
        int gr = base + ty * 8 + i;
        float p0s = 0.f, p1s = 0.f, p0d = 0.f, p1d = 0.f;
#pragma unroll
        for (int jj = 0; jj < 4; ++jj) {
            p0s = fmaf(acc[i][jj],     asv[jj],     p0s);
            p0d = fmaf(acc[i][jj],     adv[jj],     p0d);
            p1s = fmaf(acc[i][4 + jj], asv[4 + jj], p1s);
            p1d = fmaf(acc[i][4 + jj], adv[4 + jj], p1d);
        }
#pragma unroll
        for (int off = 1; off < 8; off <<= 1) {
            p0s += __shfl_xor(p0s, off);
            p0d += __shfl_xor(p0d, off);
            p1s += __shfl_xor(p1s, off);
            p1d += __shfl_xor(p1d, off);
        }
        if (gr < N) {
            float4 o0 = make_float4(acc[i][0], acc[i][1], acc[i][2], acc[i][3]);
            float4 o1 = make_float4(acc[i][4], acc[i][5], acc[i][6], acc[i][7]);
            *(float4*)(h1 + (size_t)gr * 128 + tx * 4) = o0;
            *(float4*)(h1 + (size_t)gr * 128 + 64 + tx * 4) = o1;
            if ((tx & 7) == 0) {
                int hlo = tx >> 3;
                asrc[gr * 4 + hlo]     = p0s;
                adst[gr * 4 + hlo]     = p0d;
                asrc[gr * 4 + 2 + hlo] = p1s;
                adst[gr * 4 + 2 + hlo] = p1d;
            }
        }
    }
}

// ---------------------------------------------------------------------------
// CSR build
// ---------------------------------------------------------------------------
__global__ void deg_init_kernel(int* deg, int* cursor, int N) {
    int i = blockIdx.x * 256 + threadIdx.x;
    if (i < N) { deg[i] = 1; cursor[i] = 0; }
}

__global__ void hist_kernel(const void* ei, int* deg, int E, const int* flag) {
    int i = blockIdx.x * 256 + threadIdx.x;
    if (i < E) {
        int is64 = *flag;
        int d = edge_at(ei, (long long)E + i, is64);
        atomicAdd(&deg[d], 1);
    }
}

__global__ void reduce_kernel(const int* __restrict__ deg, int* bsums, int N) {
    __shared__ int s[256];
    int tid = threadIdx.x;
    int base = blockIdx.x * 1024 + tid * 4;
    int t = 0;
#pragma unroll
    for (int u = 0; u < 4; ++u) { int idx = base + u; if (idx < N) t += deg[idx]; }
    s[tid] = t;
    __syncthreads();
    for (int off = 128; off; off >>= 1) {
        if (tid < off) s[tid] += s[tid + off];
        __syncthreads();
    }
    if (tid == 0) bsums[blockIdx.x] = s[0];
}

// parallel scan of block sums (single 128-thread block, tiles of 128)
__global__ void scan_bsums_kernel(int* bsums, int* rowptr, int nb, int N) {
    __shared__ int s[128];
    __shared__ int carry;
    int tid = threadIdx.x;
    if (tid == 0) carry = 0;
    __syncthreads();
    for (int base = 0; base < nb; base += 128) {
        int idx = base + tid;
        int v = (idx < nb) ? bsums[idx] : 0;
        s[tid] = v;
        __syncthreads();
        for (int off = 1; off < 128; off <<= 1) {
            int t = (tid >= off) ? s[tid - off] : 0;
            __syncthreads();
            s[tid] += t;
            __syncthreads();
        }
        int excl = carry + ((tid == 0) ? 0 : s[tid - 1]);
        if (idx < nb) bsums[idx] = excl;
        __syncthreads();
        if (tid == 0) carry += s[127];
        __syncthreads();
    }
    if (tid == 0) rowptr[N] = carry;
}

__global__ void scan_write_kernel(const int* __restrict__ deg,
                                  const int* __restrict__ bsums,
                                  int* __restrict__ rowptr, int N) {
    __shared__ int s[256];
    int tid = threadIdx.x;
    int base_i = blockIdx.x * 1024 + tid * 4;
    int v[4]; int t = 0;
#pragma unroll
    for (int u = 0; u < 4; ++u) {
        int idx = base_i + u;
        v[u] = (idx < N) ? deg[idx] : 0;
        t += v[u];
    }
    s[tid] = t;
    __syncthreads();
    for (int off = 1; off < 256; off <<= 1) {
        int tv = (tid >= off) ? s[tid - off] : 0;
        __syncthreads();
        s[tid] += tv;
        __syncthreads();
    }
    int excl = (tid == 0) ? 0 : s[tid - 1];
    int p = bsums[blockIdx.x] + excl;
#pragma unroll
    for (int u = 0; u < 4; ++u) {
        int idx = base_i + u;
        if (idx < N) rowptr[idx] = p;
        p += v[u];
    }
}

__global__ void scatter_kernel(const void* ei, const int* __restrict__ rowptr,
                               int* cursor, int* __restrict__ srcs,
                               int E, int ET, const int* flag) {
    int i = blockIdx.x * 256 + threadIdx.x;
    if (i < ET) {
        int is64 = *flag;
        int s, d;
        if (i < E) {
            s = edge_at(ei, i, is64);
            d = edge_at(ei, (long long)E + i, is64);
        } else {
            s = d = i - E;
        }
        int pos = rowptr[d] + atomicAdd(&cursor[d], 1);
        srcs[pos] = s;
    }
}

// ---------------------------------------------------------------------------
// Layer-1 aggregation: 128 threads = one dst node; thread = channel,
// head h = c>>5, lane l = c&31. Cooperative exp (one per edge-head); chunk's
// (w,s) packed into LDS, inner loop reads them via uniform-address
// ds_read_b64 (HW broadcast, conflict-free) -> 1 DS op/edge/wave (was 2
// bpermutes). 8 independent accumulators keep 8 h1-row loads in flight.
// Region stride 36 float2 = 72 words -> groups offset by 8 banks: the two
// head groups of a wave read disjoint banks.
// ---------------------------------------------------------------------------
__global__ __launch_bounds__(128) void agg1_kernel(
    const float* __restrict__ h1, const float* __restrict__ asrc,
    const float* __restrict__ adst, const int* __restrict__ rowptr,
    const int* __restrict__ srcs, const float* __restrict__ b1,
    float* __restrict__ g, int N) {
    __shared__ float2 ws[4][36];
    int d = blockIdx.x;
    int tid = threadIdx.x;
    int h = tid >> 5, l = tid & 31;
    int start = rowptr[d], end = rowptr[d + 1];
    int deg = end - start;
    float ad = adst[d * 4 + h];

    // phase A: per-head max, lane-parallel
    float m = -1e30f;
    for (int j = start + l; j < end; j += 32) {
        float t = asrc[srcs[j] * 4 + h] + ad;
        t = (t > 0.f) ? t : NEG_SLOPE * t;
        m = fmaxf(m, t);
    }
#pragma unroll
    for (int off = 16; off; off >>= 1) m = fmaxf(m, __shfl_xor(m, off, 32));

    // phase B: chunks of 32 edges; lane l computes w for edge l of chunk,
    // stages (w, s-bits) in LDS; all lanes of the head group read each
    // edge's pair via broadcast ds_read_b64.
    float a0 = 0.f, a1 = 0.f, a2 = 0.f, a3 = 0.f;
    float a4 = 0.f, a5 = 0.f, a6 = 0.f, a7 = 0.f;
    float lsum = 0.f;
    const float* h1c = h1 + tid;
    for (int cb = 0; cb < deg; cb += 32) {
        int cl = min(32, deg - cb);
        float wv = 0.f; int sv = 0;
        if (l < cl) {
            sv = srcs[start + cb + l];
            float t = asrc[sv * 4 + h] + ad;
            t = (t > 0.f) ? t : NEG_SLOPE * t;
            wv = __expf(t - m);
        }
        ws[h][l] = make_float2(wv, __int_as_float(sv));
        lsum += wv;   // deferred: reduced across lanes after the loop
        int e = 0;
        for (; e + 8 <= cl; e += 8) {
            float2 p0 = ws[h][e + 0], p1 = ws[h][e + 1];
            float2 p2 = ws[h][e + 2], p3 = ws[h][e + 3];
            float2 p4 = ws[h][e + 4], p5 = ws[h][e + 5];
            float2 p6 = ws[h][e + 6], p7 = ws[h][e + 7];
            a0 = fmaf(p0.x, h1c[(size_t)__float_as_int(p0.y) * 128], a0);
            a1 = fmaf(p1.x, h1c[(size_t)__float_as_int(p1.y) * 128], a1);
            a2 = fmaf(p2.x, h1c[(size_t)__float_as_int(p2.y) * 128], a2);
            a3 = fmaf(p3.x, h1c[(size_t)__float_as_int(p3.y) * 128], a3);
            a4 = fmaf(p4.x, h1c[(size_t)__float_as_int(p4.y) * 128], a4);
            a5 = fmaf(p5.x, h1c[(size_t)__float_as_int(p5.y) * 128], a5);
            a6 = fmaf(p6.x, h1c[(size_t)__float_as_int(p6.y) * 128], a6);
            a7 = fmaf(p7.x, h1c[(size_t)__float_as_int(p7.y) * 128], a7);
        }
        for (; e < cl; ++e) {
            float2 p = ws[h][e];
            a0 = fmaf(p.x, h1c[(size_t)__float_as_int(p.y) * 128], a0);
        }
    }
#pragma unroll
    for (int off = 16; off; off >>= 1) lsum += __shfl_xor(lsum, off, 32);
    float acc = ((a0 + a1) + (a2 + a3)) + ((a4 + a5) + (a6 + a7));
    float r = acc / lsum + b1[tid];
    g[(size_t)d * 128 + tid] = (r > 0.f) ? r : expm1f(r);
}

// ---------------------------------------------------------------------------
// GEMM2 + alpha2: h2[N,16] = g[N,128] @ W2[128,16]
// ---------------------------------------------------------------------------
__global__ __launch_bounds__(256) void gemm2_kernel(
    const float* __restrict__ g, const float* __restrict__ W2,
    const float* __restrict__ a_src2, const float* __restrict__ a_dst2,
    float* __restrict__ h2, float* __restrict__ asrc2, float* __restrict__ adst2,
    int N) {
    __shared__ float W2s[128 * 16];
    __shared__ float gs[16][132];
    int tid = threadIdx.x;
#pragma unroll
    for (int u = 0; u < 8; ++u) W2s[u * 256 + tid] = W2[u * 256 + tid];
    int base = blockIdx.x * 16;
#pragma unroll
    for (int p = 0; p < 2; ++p) {
        int q = tid + p * 256;
        int r = q >> 5, c4 = q & 31;
        int gr = base + r;
        float4 v = make_float4(0.f, 0.f, 0.f, 0.f);
        if (gr < N) v = *(const float4*)(g + (size_t)gr * 128 + c4 * 4);
        *(float4*)&gs[r][c4 * 4] = v;
    }
    __syncthreads();
    int ln = tid >> 4, c = tid & 15;
    int n = base + ln;
    float acc = 0.f;
#pragma unroll 8
    for (int k = 0; k < 128; ++k)
        acc = fmaf(gs[ln][k], W2s[k * 16 + c], acc);
    float s1 = acc * a_src2[c];
    float s2 = acc * a_dst2[c];
#pragma unroll
    for (int off = 8; off; off >>= 1) {
        s1 += __shfl_xor(s1, off, 16);
        s2 += __shfl_xor(s2, off, 16);
    }
    if (n < N) {
        h2[(size_t)n * 16 + c] = acc;
        if (c == 0) { asrc2[n] = s1; adst2[n] = s2; }
    }
}

// Layer-2 aggregation: 256 threads = 16 nodes x 16 channels; packed (w,s)
// LDS stage + uniform ds_read_b64 broadcast, 8-way unrolled gather.
// Region stride 20 float2 = 40 words -> the 4 groups of a wave land on
// bank offsets 0/8/16/24: disjoint.
__global__ __launch_bounds__(256) void agg2_kernel(
    const float* __restrict__ h2, const float* __restrict__ asrc2,
    const float* __restrict__ adst2, const int* __restrict__ rowptr,
    const int* __restrict__ srcs, const float* __restrict__ b2,
    float* __restrict__ out, int N) {
    __shared__ float2 ws2[16][20];
    int tid = threadIdx.x;
    int grp = tid >> 4;
    int d = blockIdx.x * 16 + grp;
    int c = tid & 15;
    if (d >= N) return;
    int start = rowptr[d], end = rowptr[d + 1];
    int deg = end - start;
    float ad = adst2[d];

    float m = -1e30f;
    for (int j = start + c; j < end; j += 16) {
        float t = asrc2[srcs[j]] + ad;
        t = (t > 0.f) ? t : NEG_SLOPE * t;
        m = fmaxf(m, t);
    }
#pragma unroll
    for (int off = 8; off; off >>= 1) m = fmaxf(m, __shfl_xor(m, off, 16));

    float a0 = 0.f, a1 = 0.f, a2 = 0.f, a3 = 0.f;
    float a4 = 0.f, a5 = 0.f, a6 = 0.f, a7 = 0.f;
    float lsum = 0.f;
    const float* h2c = h2 + c;
    for (int cb = 0; cb < deg; cb += 16) {
        int cl = min(16, deg - cb);
        float wv = 0.f; int sv = 0;
        if (c < cl) {
            sv = srcs[start + cb + c];
            float t = asrc2[sv] + ad;
            t = (t > 0.f) ? t : NEG_SLOPE * t;
            wv = __expf(t - m);
        }
        ws2[grp][c] = make_float2(wv, __int_as_float(sv));
        lsum += wv;
        int e = 0;
        for (; e + 8 <= cl; e += 8) {
            float2 p0 = ws2[grp][e + 0], p1 = ws2[grp][e + 1];
            float2 p2 = ws2[grp][e + 2], p3 = ws2[grp][e + 3];
            float2 p4 = ws2[grp][e + 4], p5 = ws2[grp][e + 5];
            float2 p6 = ws2[grp][e + 6], p7 = ws2[grp][e + 7];
            a0 = fmaf(p0.x, h2c[(size_t)__float_as_int(p0.y) * 16], a0);
            a1 = fmaf(p1.x, h2c[(size_t)__float_as_int(p1.y) * 16], a1);
            a2 = fmaf(p2.x, h2c[(size_t)__float_as_int(p2.y) * 16], a2);
            a3 = fmaf(p3.x, h2c[(size_t)__float_as_int(p3.y) * 16], a3);
            a4 = fmaf(p4.x, h2c[(size_t)__float_as_int(p4.y) * 16], a4);
            a5 = fmaf(p5.x, h2c[(size_t)__float_as_int(p5.y) * 16], a5);
            a6 = fmaf(p6.x, h2c[(size_t)__float_as_int(p6.y) * 16], a6);
            a7 = fmaf(p7.x, h2c[(size_t)__float_as_int(p7.y) * 16], a7);
        }
        for (; e < cl; ++e) {
            float2 p = ws2[grp][e];
            a0 = fmaf(p.x, h2c[(size_t)__float_as_int(p.y) * 16], a0);
        }
    }
#pragma unroll
    for (int off = 8; off; off >>= 1) lsum += __shfl_xor(lsum, off, 16);
    float acc = ((a0 + a1) + (a2 + a3)) + ((a4 + a5) + (a6 + a7));
    out[(size_t)d * 16 + c] = acc / lsum + b2[c];
}

// ---------------------------------------------------------------------------
extern "C" void kernel_launch(void* const* d_in, const int* in_sizes, int n_in,
                              void* d_out, int out_size, void* d_ws, size_t ws_size,
                              hipStream_t stream) {
    const float* x      = (const float*)d_in[0];
    const void*  ei     = d_in[1];
    const float* W1     = (const float*)d_in[2];
    const float* a_src1 = (const float*)d_in[3];
    const float* a_dst1 = (const float*)d_in[4];
    const float* b1     = (const float*)d_in[5];
    const float* W2     = (const float*)d_in[6];
    const float* a_src2 = (const float*)d_in[7];
    const float* a_dst2 = (const float*)d_in[8];
    const float* b2     = (const float*)d_in[9];

    const int N  = in_sizes[0] / 128;   // 100000
    const int E  = in_sizes[1] / 2;     // 1600000
    const int ET = E + N;

    char* w = (char*)d_ws;
    size_t off = 0;
    auto alloc = [&](size_t bytes) -> char* {
        char* p = w + off;
        off = (off + bytes + 255) & ~(size_t)255;
        return p;
    };
    float* h1     = (float*)alloc((size_t)N * 128 * 4);
    float* g      = (float*)alloc((size_t)N * 128 * 4);
    float* asrc1  = (float*)alloc((size_t)N * 4 * 4);
    float* adst1  = (float*)alloc((size_t)N * 4 * 4);
    int*   deg    = (int*)alloc((size_t)N * 4);
    int*   cursor = (int*)alloc((size_t)N * 4);
    int*   rowptr = (int*)alloc((size_t)(N + 1) * 4);
    int*   srcs   = (int*)alloc((size_t)ET * 4);
    int*   bsums  = (int*)alloc(4096);
    int*   flag   = (int*)alloc(256);
    float* h2    = h1;                       // h1 dead after agg1
    float* asrc2 = h1 + (size_t)N * 16;
    float* adst2 = asrc2 + N;

    const int nb = (N + 1023) / 1024;

    detect_fmt_kernel<<<1, 1, 0, stream>>>(ei, flag);
    gemm1_kernel<<<(N + 127) / 128, 256, 0, stream>>>(x, W1, a_src1, a_dst1,
                                                      h1, asrc1, adst1, N);
    deg_init_kernel<<<(N + 255) / 256, 256, 0, stream>>>(deg, cursor, N);
    hist_kernel<<<(E + 255) / 256, 256, 0, stream>>>(ei, deg, E, flag);
    reduce_kernel<<<nb, 256, 0, stream>>>(deg, bsums, N);
    scan_bsums_kernel<<<1, 128, 0, stream>>>(bsums, rowptr, nb, N);
    scan_write_kernel<<<nb, 256, 0, stream>>>(deg, bsums, rowptr, N);
    scatter_kernel<<<(ET + 255) / 256, 256, 0, stream>>>(ei, rowptr, cursor, srcs, E, ET, flag);
    agg1_kernel<<<N, 128, 0, stream>>>(h1, asrc1, adst1, rowptr, srcs, b1, g, N);
    gemm2_kernel<<<(N + 15) / 16, 256, 0, stream>>>(g, W2, a_src2, a_dst2, h2, asrc2, adst2, N);
    agg2_kernel<<<(N + 15) / 16, 256, 0, stream>>>(h2, asrc2, adst2, rowptr, srcs, b2, (float*)d_out, N);
}

// Round 11
// 541.640 us; speedup vs baseline: 1.3573x; 1.0012x over previous
//
#include <hip/hip_runtime.h>
#include <cstdint>
#include <cstddef>

#define NEG_SLOPE 0.2f

// ---------------------------------------------------------------------------
// N=100000, F_in=128, H=4, C1=32 (HC=128), C2=16, E=1600000 (+N self-loops).
// CSR-by-dst build (int atomics only), gather-side aggregation (no float
// atomics). GEMMs f32 vector (no fp32 MFMA on CDNA4).
// R8 measured: 549.8us, agg1 147.8 (8-way MLP). R9 measured: LDS-broadcast
// swap regressed agg1 to 154.6 (DS ops NOT the limiter; occupancy fell).
// R10: issue-throughput theory — one WAVE per dst node, float2 (8B/lane)
// h1 gather so a single wave covers the 512B row. Issue slots/edge/node
// ~12 -> ~7. 256-thread blocks = 4 independent waves/nodes, no barriers.
// launch_bounds(256,8) keeps VGPR<=64 for full occupancy.
// R11: resubmit of R10 (GPUAcquisitionTimeout); audit clean.
// ---------------------------------------------------------------------------

__device__ __forceinline__ int edge_at(const void* ei, long long idx, int is64) {
    if (is64) return (int)((const long long*)ei)[idx];
    return ((const int*)ei)[idx];
}

__global__ void detect_fmt_kernel(const void* ei, int* flag) {
    if (threadIdx.x == 0 && blockIdx.x == 0) {
        const unsigned* u = (const unsigned*)ei;
        int zc = 0;
        for (int i = 0; i < 128; ++i) zc += (u[2 * i + 1] == 0u);
        *flag = (zc >= 100) ? 1 : 0;
    }
}

// ---------------------------------------------------------------------------
// GEMM1: h1[N,128] = x[N,128] @ W1[128,128] + fused alpha_src/dst epilogue.
// ---------------------------------------------------------------------------
__global__ __launch_bounds__(256) void gemm1_kernel(
    const float* __restrict__ x, const float* __restrict__ W,
    const float* __restrict__ a_src, const float* __restrict__ a_dst,
    float* __restrict__ h1, float* __restrict__ asrc, float* __restrict__ adst,
    int N) {
    __shared__ float As2[32][132];
    __shared__ float Bs[32][128];
    const int tid = threadIdx.x;
    const int tx = tid & 15, ty = tid >> 4;
    const int base = blockIdx.x * 128;

    float acc[8][8];
#pragma unroll
    for (int i = 0; i < 8; ++i)
#pragma unroll
        for (int j = 0; j < 8; ++j) acc[i][j] = 0.f;

    for (int kb = 0; kb < 128; kb += 32) {
        {   // stage x tile transposed: As2[k][row]
            const int r0 = tid >> 3;   // 0..31
            const int q  = tid & 7;    // k-quad
#pragma unroll
            for (int p = 0; p < 4; ++p) {
                int r = r0 + p * 32;
                int gr = base + r;
                float4 v = make_float4(0.f, 0.f, 0.f, 0.f);
                if (gr < N) v = *(const float4*)(x + (size_t)gr * 128 + kb + q * 4);
                As2[q * 4 + 0][r] = v.x; As2[q * 4 + 1][r] = v.y;
                As2[q * 4 + 2][r] = v.z; As2[q * 4 + 3][r] = v.w;
            }
        }
        {   // stage W tile [32 k][128 cols]
            const int k0 = tid >> 5;
            const int f  = tid & 31;
#pragma unroll
            for (int p = 0; p < 4; ++p) {
                int kk = k0 + p * 8;
                float4 v = *(const float4*)(W + (size_t)(kb + kk) * 128 + f * 4);
                *(float4*)&Bs[kk][f * 4] = v;
            }
        }
        __syncthreads();
#pragma unroll 4
        for (int kk = 0; kk < 32; ++kk) {
            float4 a0 = *(const float4*)&As2[kk][ty * 8];
            float4 a1 = *(const float4*)&As2[kk][ty * 8 + 4];
            float a[8] = {a0.x, a0.y, a0.z, a0.w, a1.x, a1.y, a1.z, a1.w};
            float4 b0 = *(const float4*)&Bs[kk][tx * 4];
            float4 b1 = *(const float4*)&Bs[kk][64 + tx * 4];
            float b[8] = {b0.x, b0.y, b0.z, b0.w, b1.x, b1.y, b1.z, b1.w};
#pragma unroll
            for (int i = 0; i < 8; ++i)
#pragma unroll
                for (int j = 0; j < 8; ++j)
                    acc[i][j] = fmaf(a[i], b[j], acc[i][j]);
        }
        __syncthreads();
    }

    float asv[8], adv[8];
#pragma unroll
    for (int jj = 0; jj < 4; ++jj) {
        asv[jj]     = a_src[tx * 4 + jj];
        asv[4 + jj] = a_src[64 + tx * 4 + jj];
        adv[jj]     = a_dst[tx * 4 + jj];
        adv[4 + jj] = a_dst[64 + tx * 4 + jj];
    }

#pragma unroll
    for (int i = 0; i < 8; ++i) {
        int gr = base + ty * 8 + i;
        float p0s = 0.f, p1s = 0.f, p0d = 0.f, p1d = 0.f;
#pragma unroll
        for (int jj = 0; jj < 4; ++jj) {
            p0s = fmaf(acc[i][jj],     asv[jj],     p0s);
            p0d = fmaf(acc[i][jj],     adv[jj],     p0d);
            p1s = fmaf(acc[i][4 + jj], asv[4 + jj], p1s);
            p1d = fmaf(acc[i][4 + jj], adv[4 + jj], p1d);
        }
#pragma unroll
        for (int off = 1; off < 8; off <<= 1) {
            p0s += __shfl_xor(p0s, off);
            p0d += __shfl_xor(p0d, off);
            p1s += __shfl_xor(p1s, off);
            p1d += __shfl_xor(p1d, off);
        }
        if (gr < N) {
            float4 o0 = make_float4(acc[i][0], acc[i][1], acc[i][2], acc[i][3]);
            float4 o1 = make_float4(acc[i][4], acc[i][5], acc[i][6], acc[i][7]);
            *(float4*)(h1 + (size_t)gr * 128 + tx * 4) = o0;
            *(float4*)(h1 + (size_t)gr * 128 + 64 + tx * 4) = o1;
            if ((tx & 7) == 0) {
                int hlo = tx >> 3;
                asrc[gr * 4 + hlo]     = p0s;
                adst[gr * 4 + hlo]     = p0d;
                asrc[gr * 4 + 2 + hlo] = p1s;
                adst[gr * 4 + 2 + hlo] = p1d;
            }
        }
    }
}

// ---------------------------------------------------------------------------
// CSR build
// ---------------------------------------------------------------------------
__global__ void deg_init_kernel(int* deg, int* cursor, int N) {
    int i = blockIdx.x * 256 + threadIdx.x;
    if (i < N) { deg[i] = 1; cursor[i] = 0; }
}

__global__ void hist_kernel(const void* ei, int* deg, int E, const int* flag) {
    int i = blockIdx.x * 256 + threadIdx.x;
    if (i < E) {
        int is64 = *flag;
        int d = edge_at(ei, (long long)E + i, is64);
        atomicAdd(&deg[d], 1);
    }
}

__global__ void reduce_kernel(const int* __restrict__ deg, int* bsums, int N) {
    __shared__ int s[256];
    int tid = threadIdx.x;
    int base = blockIdx.x * 1024 + tid * 4;
    int t = 0;
#pragma unroll
    for (int u = 0; u < 4; ++u) { int idx = base + u; if (idx < N) t += deg[idx]; }
    s[tid] = t;
    __syncthreads();
    for (int off = 128; off; off >>= 1) {
        if (tid < off) s[tid] += s[tid + off];
        __syncthreads();
    }
    if (tid == 0) bsums[blockIdx.x] = s[0];
}

// parallel scan of block sums (single 128-thread block, tiles of 128)
__global__ void scan_bsums_kernel(int* bsums, int* rowptr, int nb, int N) {
    __shared__ int s[128];
    __shared__ int carry;
    int tid = threadIdx.x;
    if (tid == 0) carry = 0;
    __syncthreads();
    for (int base = 0; base < nb; base += 128) {
        int idx = base + tid;
        int v = (idx < nb) ? bsums[idx] : 0;
        s[tid] = v;
        __syncthreads();
        for (int off = 1; off < 128; off <<= 1) {
            int t = (tid >= off) ? s[tid - off] : 0;
            __syncthreads();
            s[tid] += t;
            __syncthreads();
        }
        int excl = carry + ((tid == 0) ? 0 : s[tid - 1]);
        if (idx < nb) bsums[idx] = excl;
        __syncthreads();
        if (tid == 0) carry += s[127];
        __syncthreads();
    }
    if (tid == 0) rowptr[N] = carry;
}

__global__ void scan_write_kernel(const int* __restrict__ deg,
                                  const int* __restrict__ bsums,
                                  int* __restrict__ rowptr, int N) {
    __shared__ int s[256];
    int tid = threadIdx.x;
    int base_i = blockIdx.x * 1024 + tid * 4;
    int v[4]; int t = 0;
#pragma unroll
    for (int u = 0; u < 4; ++u) {
        int idx = base_i + u;
        v[u] = (idx < N) ? deg[idx] : 0;
        t += v[u];
    }
    s[tid] = t;
    __syncthreads();
    for (int off = 1; off < 256; off <<= 1) {
        int tv = (tid >= off) ? s[tid - off] : 0;
        __syncthreads();
        s[tid] += tv;
        __syncthreads();
    }
    int excl = (tid == 0) ? 0 : s[tid - 1];
    int p = bsums[blockIdx.x] + excl;
#pragma unroll
    for (int u = 0; u < 4; ++u) {
        int idx = base_i + u;
        if (idx < N) rowptr[idx] = p;
        p += v[u];
    }
}

__global__ void scatter_kernel(const void* ei, const int* __restrict__ rowptr,
                               int* cursor, int* __restrict__ srcs,
                               int E, int ET, const int* flag) {
    int i = blockIdx.x * 256 + threadIdx.x;
    if (i < ET) {
        int is64 = *flag;
        int s, d;
        if (i < E) {
            s = edge_at(ei, i, is64);
            d = edge_at(ei, (long long)E + i, is64);
        } else {
            s = d = i - E;
        }
        int pos = rowptr[d] + atomicAdd(&cursor[d], 1);
        srcs[pos] = s;
    }
}

// ---------------------------------------------------------------------------
// Layer-1 aggregation: ONE WAVE per dst node; lane w owns channels
// [2w, 2w+1] (float2 gather: 64 lanes x 8B = full 512B row per load).
// Head h = w>>4; 16-lane head groups do cooperative exp on chunks of 16
// edges; packed (w,s) staged in LDS, read back via broadcast ds_read_b64
// (group addresses hit banks 0/4/8/12 -> conflict-free). 8 independent
// float2 accumulators for MLP. 256-thread block = 4 independent waves.
// ---------------------------------------------------------------------------
__global__ __launch_bounds__(256, 8) void agg1_kernel(
    const float* __restrict__ h1, const float* __restrict__ asrc,
    const float* __restrict__ adst, const int* __restrict__ rowptr,
    const int* __restrict__ srcs, const float* __restrict__ b1,
    float* __restrict__ g, int N) {
    __shared__ float2 ws[4][4][18];   // [wave][head][edge slot], pad 18
    int tid = threadIdx.x;
    int wid = tid >> 6;       // wave in block
    int w   = tid & 63;       // lane in wave
    int d   = blockIdx.x * 4 + wid;
    if (d >= N) return;       // wave-uniform
    int h   = w >> 4;         // head
    int el  = w & 15;         // edge lane within head group
    int c0  = 2 * w;          // first owned channel
    int start = rowptr[d], end = rowptr[d + 1];
    int deg = end - start;
    float ad = adst[d * 4 + h];

    // phase A: per-head max, 16-lane parallel
    float m = -1e30f;
    for (int j = start + el; j < end; j += 16) {
        float t = asrc[srcs[j] * 4 + h] + ad;
        t = (t > 0.f) ? t : NEG_SLOPE * t;
        m = fmaxf(m, t);
    }
#pragma unroll
    for (int off = 8; off; off >>= 1) m = fmaxf(m, __shfl_xor(m, off, 16));

    // phase B: chunks of 16 edges; lane el computes w for edge el of chunk,
    // stages (w, s-bits) in LDS; group reads each edge's pair via broadcast.
    float2 a0 = {0.f, 0.f}, a1 = {0.f, 0.f}, a2 = {0.f, 0.f}, a3 = {0.f, 0.f};
    float2 a4 = {0.f, 0.f}, a5 = {0.f, 0.f}, a6 = {0.f, 0.f}, a7 = {0.f, 0.f};
    float lsum = 0.f;
    const float* h1c = h1 + c0;
    for (int cb = 0; cb < deg; cb += 16) {
        int cl = min(16, deg - cb);
        float wv = 0.f; int sv = 0;
        if (el < cl) {
            sv = srcs[start + cb + el];
            float t = asrc[sv * 4 + h] + ad;
            t = (t > 0.f) ? t : NEG_SLOPE * t;
            wv = __expf(t - m);
        }
        ws[wid][h][el] = make_float2(wv, __int_as_float(sv));
        lsum += wv;   // deferred: reduced across the group after the loop
        int e = 0;
        for (; e + 8 <= cl; e += 8) {
            float2 p0 = ws[wid][h][e + 0], p1 = ws[wid][h][e + 1];
            float2 p2 = ws[wid][h][e + 2], p3 = ws[wid][h][e + 3];
            float2 p4 = ws[wid][h][e + 4], p5 = ws[wid][h][e + 5];
            float2 p6 = ws[wid][h][e + 6], p7 = ws[wid][h][e + 7];
            float2 v0 = *(const float2*)(h1c + (size_t)__float_as_int(p0.y) * 128);
            float2 v1 = *(const float2*)(h1c + (size_t)__float_as_int(p1.y) * 128);
            float2 v2 = *(const float2*)(h1c + (size_t)__float_as_int(p2.y) * 128);
            float2 v3 = *(const float2*)(h1c + (size_t)__float_as_int(p3.y) * 128);
            float2 v4 = *(const float2*)(h1c + (size_t)__float_as_int(p4.y) * 128);
            float2 v5 = *(const float2*)(h1c + (size_t)__float_as_int(p5.y) * 128);
            float2 v6 = *(const float2*)(h1c + (size_t)__float_as_int(p6.y) * 128);
            float2 v7 = *(const float2*)(h1c + (size_t)__float_as_int(p7.y) * 128);
            a0.x = fmaf(p0.x, v0.x, a0.x); a0.y = fmaf(p0.x, v0.y, a0.y);
            a1.x = fmaf(p1.x, v1.x, a1.x); a1.y = fmaf(p1.x, v1.y, a1.y);
            a2.x = fmaf(p2.x, v2.x, a2.x); a2.y = fmaf(p2.x, v2.y, a2.y);
            a3.x = fmaf(p3.x, v3.x, a3.x); a3.y = fmaf(p3.x, v3.y, a3.y);
            a4.x = fmaf(p4.x, v4.x, a4.x); a4.y = fmaf(p4.x, v4.y, a4.y);
            a5.x = fmaf(p5.x, v5.x, a5.x); a5.y = fmaf(p5.x, v5.y, a5.y);
            a6.x = fmaf(p6.x, v6.x, a6.x); a6.y = fmaf(p6.x, v6.y, a6.y);
            a7.x = fmaf(p7.x, v7.x, a7.x); a7.y = fmaf(p7.x, v7.y, a7.y);
        }
        for (; e < cl; ++e) {
            float2 p = ws[wid][h][e];
            float2 v = *(const float2*)(h1c + (size_t)__float_as_int(p.y) * 128);
            a0.x = fmaf(p.x, v.x, a0.x); a0.y = fmaf(p.x, v.y, a0.y);
        }
    }
#pragma unroll
    for (int off = 8; off; off >>= 1) lsum += __shfl_xor(lsum, off, 16);
    float accx = ((a0.x + a1.x) + (a2.x + a3.x)) + ((a4.x + a5.x) + (a6.x + a7.x));
    float accy = ((a0.y + a1.y) + (a2.y + a3.y)) + ((a4.y + a5.y) + (a6.y + a7.y));
    float2 bb = *(const float2*)(b1 + c0);
    float r0 = accx / lsum + bb.x;
    float r1 = accy / lsum + bb.y;
    r0 = (r0 > 0.f) ? r0 : expm1f(r0);
    r1 = (r1 > 0.f) ? r1 : expm1f(r1);
    *(float2*)(g + (size_t)d * 128 + c0) = make_float2(r0, r1);
}

// ---------------------------------------------------------------------------
// GEMM2 + alpha2: h2[N,16] = g[N,128] @ W2[128,16]
// ---------------------------------------------------------------------------
__global__ __launch_bounds__(256) void gemm2_kernel(
    const float* __restrict__ g, const float* __restrict__ W2,
    const float* __restrict__ a_src2, const float* __restrict__ a_dst2,
    float* __restrict__ h2, float* __restrict__ asrc2, float* __restrict__ adst2,
    int N) {
    __shared__ float W2s[128 * 16];
    __shared__ float gs[16][132];
    int tid = threadIdx.x;
#pragma unroll
    for (int u = 0; u < 8; ++u) W2s[u * 256 + tid] = W2[u * 256 + tid];
    int base = blockIdx.x * 16;
#pragma unroll
    for (int p = 0; p < 2; ++p) {
        int q = tid + p * 256;
        int r = q >> 5, c4 = q & 31;
        int gr = base + r;
        float4 v = make_float4(0.f, 0.f, 0.f, 0.f);
        if (gr < N) v = *(const float4*)(g + (size_t)gr * 128 + c4 * 4);
        *(float4*)&gs[r][c4 * 4] = v;
    }
    __syncthreads();
    int ln = tid >> 4, c = tid & 15;
    int n = base + ln;
    float acc = 0.f;
#pragma unroll 8
    for (int k = 0; k < 128; ++k)
        acc = fmaf(gs[ln][k], W2s[k * 16 + c], acc);
    float s1 = acc * a_src2[c];
    float s2 = acc * a_dst2[c];
#pragma unroll
    for (int off = 8; off; off >>= 1) {
        s1 += __shfl_xor(s1, off, 16);
        s2 += __shfl_xor(s2, off, 16);
    }
    if (n < N) {
        h2[(size_t)n * 16 + c] = acc;
        if (c == 0) { asrc2[n] = s1; adst2[n] = s2; }
    }
}

// Layer-2 aggregation: 256 threads = 16 nodes x 16 channels; packed (w,s)
// LDS stage + uniform ds_read_b64 broadcast, 8-way unrolled gather.
__global__ __launch_bounds__(256) void agg2_kernel(
    const float* __restrict__ h2, const float* __restrict__ asrc2,
    const float* __restrict__ adst2, const int* __restrict__ rowptr,
    const int* __restrict__ srcs, const float* __restrict__ b2,
    float* __restrict__ out, int N) {
    __shared__ float2 ws2[16][20];
    int tid = threadIdx.x;
    int grp = tid >> 4;
    int d = blockIdx.x * 16 + grp;
    int c = tid & 15;
    if (d >= N) return;
    int start = rowptr[d], end = rowptr[d + 1];
    int deg = end - start;
    float ad = adst2[d];

    float m = -1e30f;
    for (int j = start + c; j < end; j += 16) {
        float t = asrc2[srcs[j]] + ad;
        t = (t > 0.f) ? t : NEG_SLOPE * t;
        m = fmaxf(m, t);
    }
#pragma unroll
    for (int off = 8; off; off >>= 1) m = fmaxf(m, __shfl_xor(m, off, 16));

    float a0 = 0.f, a1 = 0.f, a2 = 0.f, a3 = 0.f;
    float a4 = 0.f, a5 = 0.f, a6 = 0.f, a7 = 0.f;
    float lsum = 0.f;
    const float* h2c = h2 + c;
    for (int cb = 0; cb < deg; cb += 16) {
        int cl = min(16, deg - cb);
        float wv = 0.f; int sv = 0;
        if (c < cl) {
            sv = srcs[start + cb + c];
            float t = asrc2[sv] + ad;
            t = (t > 0.f) ? t : NEG_SLOPE * t;
            wv = __expf(t - m);
        }
        ws2[grp][c] = make_float2(wv, __int_as_float(sv));
        lsum += wv;
        int e = 0;
        for (; e + 8 <= cl; e += 8) {
            float2 p0 = ws2[grp][e + 0], p1 = ws2[grp][e + 1];
            float2 p2 = ws2[grp][e + 2], p3 = ws2[grp][e + 3];
            float2 p4 = ws2[grp][e + 4], p5 = ws2[grp][e + 5];
            float2 p6 = ws2[grp][e + 6], p7 = ws2[grp][e + 7];
            a0 = fmaf(p0.x, h2c[(size_t)__float_as_int(p0.y) * 16], a0);
            a1 = fmaf(p1.x, h2c[(size_t)__float_as_int(p1.y) * 16], a1);
            a2 = fmaf(p2.x, h2c[(size_t)__float_as_int(p2.y) * 16], a2);
            a3 = fmaf(p3.x, h2c[(size_t)__float_as_int(p3.y) * 16], a3);
            a4 = fmaf(p4.x, h2c[(size_t)__float_as_int(p4.y) * 16], a4);
            a5 = fmaf(p5.x, h2c[(size_t)__float_as_int(p5.y) * 16], a5);
            a6 = fmaf(p6.x, h2c[(size_t)__float_as_int(p6.y) * 16], a6);
            a7 = fmaf(p7.x, h2c[(size_t)__float_as_int(p7.y) * 16], a7);
        }
        for (; e < cl; ++e) {
            float2 p = ws2[grp][e];
            a0 = fmaf(p.x, h2c[(size_t)__float_as_int(p.y) * 16], a0);
        }
    }
#pragma unroll
    for (int off = 8; off; off >>= 1) lsum += __shfl_xor(lsum, off, 16);
    float acc = ((a0 + a1) + (a2 + a3)) + ((a4 + a5) + (a6 + a7));
    out[(size_t)d * 16 + c] = acc / lsum + b2[c];
}

// ---------------------------------------------------------------------------
extern "C" void kernel_launch(void* const* d_in, const int* in_sizes, int n_in,
                              void* d_out, int out_size, void* d_ws, size_t ws_size,
                              hipStream_t stream) {
    const float* x      = (const float*)d_in[0];
    const void*  ei     = d_in[1];
    const float* W1     = (const float*)d_in[2];
    const float* a_src1 = (const float*)d_in[3];
    const float* a_dst1 = (const float*)d_in[4];
    const float* b1     = (const float*)d_in[5];
    const float* W2     = (const float*)d_in[6];
    const float* a_src2 = (const float*)d_in[7];
    const float* a_dst2 = (const float*)d_in[8];
    const float* b2     = (const float*)d_in[9];

    const int N  = in_sizes[0] / 128;   // 100000
    const int E  = in_sizes[1] / 2;     // 1600000
    const int ET = E + N;

    char* w = (char*)d_ws;
    size_t off = 0;
    auto alloc = [&](size_t bytes) -> char* {
        char* p = w + off;
        off = (off + bytes + 255) & ~(size_t)255;
        return p;
    };
    float* h1     = (float*)alloc((size_t)N * 128 * 4);
    float* g      = (float*)alloc((size_t)N * 128 * 4);
    float* asrc1  = (float*)alloc((size_t)N * 4 * 4);
    float* adst1  = (float*)alloc((size_t)N * 4 * 4);
    int*   deg    = (int*)alloc((size_t)N * 4);
    int*   cursor = (int*)alloc((size_t)N * 4);
    int*   rowptr = (int*)alloc((size_t)(N + 1) * 4);
    int*   srcs   = (int*)alloc((size_t)ET * 4);
    int*   bsums  = (int*)alloc(4096);
    int*   flag   = (int*)alloc(256);
    float* h2    = h1;                       // h1 dead after agg1
    float* asrc2 = h1 + (size_t)N * 16;
    float* adst2 = asrc2 + N;

    const int nb = (N + 1023) / 1024;

    detect_fmt_kernel<<<1, 1, 0, stream>>>(ei, flag);
    gemm1_kernel<<<(N + 127) / 128, 256, 0, stream>>>(x, W1, a_src1, a_dst1,
                                                      h1, asrc1, adst1, N);
    deg_init_kernel<<<(N + 255) / 256, 256, 0, stream>>>(deg, cursor, N);
    hist_kernel<<<(E + 255) / 256, 256, 0, stream>>>(ei, deg, E, flag);
    reduce_kernel<<<nb, 256, 0, stream>>>(deg, bsums, N);
    scan_bsums_kernel<<<1, 128, 0, stream>>>(bsums, rowptr, nb, N);
    scan_write_kernel<<<nb, 256, 0, stream>>>(deg, bsums, rowptr, N);
    scatter_kernel<<<(ET + 255) / 256, 256, 0, stream>>>(ei, rowptr, cursor, srcs, E, ET, flag);
    agg1_kernel<<<(N + 3) / 4, 256, 0, stream>>>(h1, asrc1, adst1, rowptr, srcs, b1, g, N);
    gemm2_kernel<<<(N + 15) / 16, 256, 0, stream>>>(g, W2, a_src2, a_dst2, h2, asrc2, adst2, N);
    agg2_kernel<<<(N + 15) / 16, 256, 0, stream>>>(h2, asrc2, adst2, rowptr, srcs, b2, (float*)d_out, N);
}

// Round 12
// 523.380 us; speedup vs baseline: 1.4047x; 1.0349x over previous
//
#include <hip/hip_runtime.h>
#include <cstdint>
#include <cstddef>

#define NEG_SLOPE 0.2f

// ---------------------------------------------------------------------------
// N=100000, F_in=128, H=4, C1=32 (HC=128), C2=16, E=1600000 (+N self-loops).
// CSR-by-dst build (int atomics only), gather-side aggregation (no float
// atomics). GEMMs f32 vector (no fp32 MFMA on CDNA4).
// Measured: R8 549.8 total / agg1 147.8 (8-way shfl, 128thr). R9 agg1 LDS
// swap -> 154.6 (regress). R11 wave-per-node -> 161.2, +150MB traffic
// (float2-store RFO + VGPR squeeze). agg1 gather ~ traffic floor at f32.
// R12: agg1 reverted to R8 structure; gemm2+alpha2 FUSED into agg1 epilogue
// (g never hits HBM: -51MB write, -51MB read, -1 launch). h2/asrc2/adst2
// relocate to g's workspace region (h1 still read by agg1 -> no alias).
// agg2 stays in R9 LDS-broadcast form (best measured).
// ---------------------------------------------------------------------------

__device__ __forceinline__ int edge_at(const void* ei, long long idx, int is64) {
    if (is64) return (int)((const long long*)ei)[idx];
    return ((const int*)ei)[idx];
}

__global__ void detect_fmt_kernel(const void* ei, int* flag) {
    if (threadIdx.x == 0 && blockIdx.x == 0) {
        const unsigned* u = (const unsigned*)ei;
        int zc = 0;
        for (int i = 0; i < 128; ++i) zc += (u[2 * i + 1] == 0u);
        *flag = (zc >= 100) ? 1 : 0;
    }
}

// ---------------------------------------------------------------------------
// GEMM1: h1[N,128] = x[N,128] @ W1[128,128] + fused alpha_src/dst epilogue.
// ---------------------------------------------------------------------------
__global__ __launch_bounds__(256) void gemm1_kernel(
    const float* __restrict__ x, const float* __restrict__ W,
    const float* __restrict__ a_src, const float* __restrict__ a_dst,
    float* __restrict__ h1, float* __restrict__ asrc, float* __restrict__ adst,
    int N) {
    __shared__ float As2[32][132];
    __shared__ float Bs[32][128];
    const int tid = threadIdx.x;
    const int tx = tid & 15, ty = tid >> 4;
    const int base = blockIdx.x * 128;

    float acc[8][8];
#pragma unroll
    for (int i = 0; i < 8; ++i)
#pragma unroll
        for (int j = 0; j < 8; ++j) acc[i][j] = 0.f;

    for (int kb = 0; kb < 128; kb += 32) {
        {   // stage x tile transposed: As2[k][row]
            const int r0 = tid >> 3;   // 0..31
            const int q  = tid & 7;    // k-quad
#pragma unroll
            for (int p = 0; p < 4; ++p) {
                int r = r0 + p * 32;
                int gr = base + r;
                float4 v = make_float4(0.f, 0.f, 0.f, 0.f);
                if (gr < N) v = *(const float4*)(x + (size_t)gr * 128 + kb + q * 4);
                As2[q * 4 + 0][r] = v.x; As2[q * 4 + 1][r] = v.y;
                As2[q * 4 + 2][r] = v.z; As2[q * 4 + 3][r] = v.w;
            }
        }
        {   // stage W tile [32 k][128 cols]
            const int k0 = tid >> 5;
            const int f  = tid & 31;
#pragma unroll
            for (int p = 0; p < 4; ++p) {
                int kk = k0 + p * 8;
                float4 v = *(const float4*)(W + (size_t)(kb + kk) * 128 + f * 4);
                *(float4*)&Bs[kk][f * 4] = v;
            }
        }
        __syncthreads();
#pragma unroll 4
        for (int kk = 0; kk < 32; ++kk) {
            float4 a0 = *(const float4*)&As2[kk][ty * 8];
            float4 a1 = *(const float4*)&As2[kk][ty * 8 + 4];
            float a[8] = {a0.x, a0.y, a0.z, a0.w, a1.x, a1.y, a1.z, a1.w};
            float4 b0 = *(const float4*)&Bs[kk][tx * 4];
            float4 b1 = *(const float4*)&Bs[kk][64 + tx * 4];
            float b[8] = {b0.x, b0.y, b0.z, b0.w, b1.x, b1.y, b1.z, b1.w};
#pragma unroll
            for (int i = 0; i < 8; ++i)
#pragma unroll
                for (int j = 0; j < 8; ++j)
                    acc[i][j] = fmaf(a[i], b[j], acc[i][j]);
        }
        __syncthreads();
    }

    float asv[8], adv[8];
#pragma unroll
    for (int jj = 0; jj < 4; ++jj) {
        asv[jj]     = a_src[tx * 4 + jj];
        asv[4 + jj] = a_src[64 + tx * 4 + jj];
        adv[jj]     = a_dst[tx * 4 + jj];
        adv[4 + jj] = a_dst[64 + tx * 4 + jj];
    }

#pragma unroll
    for (int i = 0; i < 8; ++i) {
        int gr = base + ty * 8 + i;
        float p0s = 0.f, p1s = 0.f, p0d = 0.f, p1d = 0.f;
#pragma unroll
        for (int jj = 0; jj < 4; ++jj) {
            p0s = fmaf(acc[i][jj],     asv[jj],     p0s);
            p0d = fmaf(acc[i][jj],     adv[jj],     p0d);
            p1s = fmaf(acc[i][4 + jj], asv[4 + jj], p1s);
            p1d = fmaf(acc[i][4 + jj], adv[4 + jj], p1d);
        }
#pragma unroll
        for (int off = 1; off < 8; off <<= 1) {
            p0s += __shfl_xor(p0s, off);
            p0d += __shfl_xor(p0d, off);
            p1s += __shfl_xor(p1s, off);
            p1d += __shfl_xor(p1d, off);
        }
        if (gr < N) {
            float4 o0 = make_float4(acc[i][0], acc[i][1], acc[i][2], acc[i][3]);
            float4 o1 = make_float4(acc[i][4], acc[i][5], acc[i][6], acc[i][7]);
            *(float4*)(h1 + (size_t)gr * 128 + tx * 4) = o0;
            *(float4*)(h1 + (size_t)gr * 128 + 64 + tx * 4) = o1;
            if ((tx & 7) == 0) {
                int hlo = tx >> 3;
                asrc[gr * 4 + hlo]     = p0s;
                adst[gr * 4 + hlo]     = p0d;
                asrc[gr * 4 + 2 + hlo] = p1s;
                adst[gr * 4 + 2 + hlo] = p1d;
            }
        }
    }
}

// ---------------------------------------------------------------------------
// CSR build
// ---------------------------------------------------------------------------
__global__ void deg_init_kernel(int* deg, int* cursor, int N) {
    int i = blockIdx.x * 256 + threadIdx.x;
    if (i < N) { deg[i] = 1; cursor[i] = 0; }
}

__global__ void hist_kernel(const void* ei, int* deg, int E, const int* flag) {
    int i = blockIdx.x * 256 + threadIdx.x;
    if (i < E) {
        int is64 = *flag;
        int d = edge_at(ei, (long long)E + i, is64);
        atomicAdd(&deg[d], 1);
    }
}

__global__ void reduce_kernel(const int* __restrict__ deg, int* bsums, int N) {
    __shared__ int s[256];
    int tid = threadIdx.x;
    int base = blockIdx.x * 1024 + tid * 4;
    int t = 0;
#pragma unroll
    for (int u = 0; u < 4; ++u) { int idx = base + u; if (idx < N) t += deg[idx]; }
    s[tid] = t;
    __syncthreads();
    for (int off = 128; off; off >>= 1) {
        if (tid < off) s[tid] += s[tid + off];
        __syncthreads();
    }
    if (tid == 0) bsums[blockIdx.x] = s[0];
}

// parallel scan of block sums (single 128-thread block, tiles of 128)
__global__ void scan_bsums_kernel(int* bsums, int* rowptr, int nb, int N) {
    __shared__ int s[128];
    __shared__ int carry;
    int tid = threadIdx.x;
    if (tid == 0) carry = 0;
    __syncthreads();
    for (int base = 0; base < nb; base += 128) {
        int idx = base + tid;
        int v = (idx < nb) ? bsums[idx] : 0;
        s[tid] = v;
        __syncthreads();
        for (int off = 1; off < 128; off <<= 1) {
            int t = (tid >= off) ? s[tid - off] : 0;
            __syncthreads();
            s[tid] += t;
            __syncthreads();
        }
        int excl = carry + ((tid == 0) ? 0 : s[tid - 1]);
        if (idx < nb) bsums[idx] = excl;
        __syncthreads();
        if (tid == 0) carry += s[127];
        __syncthreads();
    }
    if (tid == 0) rowptr[N] = carry;
}

__global__ void scan_write_kernel(const int* __restrict__ deg,
                                  const int* __restrict__ bsums,
                                  int* __restrict__ rowptr, int N) {
    __shared__ int s[256];
    int tid = threadIdx.x;
    int base_i = blockIdx.x * 1024 + tid * 4;
    int v[4]; int t = 0;
#pragma unroll
    for (int u = 0; u < 4; ++u) {
        int idx = base_i + u;
        v[u] = (idx < N) ? deg[idx] : 0;
        t += v[u];
    }
    s[tid] = t;
    __syncthreads();
    for (int off = 1; off < 256; off <<= 1) {
        int tv = (tid >= off) ? s[tid - off] : 0;
        __syncthreads();
        s[tid] += tv;
        __syncthreads();
    }
    int excl = (tid == 0) ? 0 : s[tid - 1];
    int p = bsums[blockIdx.x] + excl;
#pragma unroll
    for (int u = 0; u < 4; ++u) {
        int idx = base_i + u;
        if (idx < N) rowptr[idx] = p;
        p += v[u];
    }
}

__global__ void scatter_kernel(const void* ei, const int* __restrict__ rowptr,
                               int* cursor, int* __restrict__ srcs,
                               int E, int ET, const int* flag) {
    int i = blockIdx.x * 256 + threadIdx.x;
    if (i < ET) {
        int is64 = *flag;
        int s, d;
        if (i < E) {
            s = edge_at(ei, i, is64);
            d = edge_at(ei, (long long)E + i, is64);
        } else {
            s = d = i - E;
        }
        int pos = rowptr[d] + atomicAdd(&cursor[d], 1);
        srcs[pos] = s;
    }
}

// ---------------------------------------------------------------------------
// Layer-1 aggregation + FUSED layer-2 GEMM/alpha epilogue.
// Main loop = R8 structure (measured 147.8us): 128 threads = one dst node;
// thread = channel, head h = c>>5, lane l = c&31; cooperative exp, shuffle
// broadcast, 8-way unrolled gather. Epilogue: g-row staged in LDS (never
// written to HBM); h2[d][0:16] = g_row @ W2 via 8 slices x 16ch threads +
// cross-wave LDS reduce; alpha2 via 16-lane shuffle reduce.
// ---------------------------------------------------------------------------
__global__ __launch_bounds__(128) void agg1_kernel(
    const float* __restrict__ h1, const float* __restrict__ asrc,
    const float* __restrict__ adst, const int* __restrict__ rowptr,
    const int* __restrict__ srcs, const float* __restrict__ b1,
    const float* __restrict__ W2, const float* __restrict__ a_src2,
    const float* __restrict__ a_dst2, float* __restrict__ h2,
    float* __restrict__ asrc2, float* __restrict__ adst2, int N) {
    __shared__ float gs[128];
    __shared__ float red[32];
    int d = blockIdx.x;
    int tid = threadIdx.x;
    int h = tid >> 5, l = tid & 31;
    int start = rowptr[d], end = rowptr[d + 1];
    int deg = end - start;
    float ad = adst[d * 4 + h];

    // phase A: per-head max, lane-parallel
    float m = -1e30f;
    for (int j = start + l; j < end; j += 32) {
        float t = asrc[srcs[j] * 4 + h] + ad;
        t = (t > 0.f) ? t : NEG_SLOPE * t;
        m = fmaxf(m, t);
    }
#pragma unroll
    for (int off = 16; off; off >>= 1) m = fmaxf(m, __shfl_xor(m, off, 32));

    // phase B: chunks of 32 edges; lane l computes w for edge l of chunk;
    // 8 independent accumulators keep 8 h1-row loads in flight.
    float a0 = 0.f, a1 = 0.f, a2 = 0.f, a3 = 0.f;
    float a4 = 0.f, a5 = 0.f, a6 = 0.f, a7 = 0.f;
    float lsum = 0.f;
    const float* h1c = h1 + tid;
    for (int cb = 0; cb < deg; cb += 32) {
        int cl = min(32, deg - cb);
        float wv = 0.f; int sv = 0;
        if (l < cl) {
            sv = srcs[start + cb + l];
            float t = asrc[sv * 4 + h] + ad;
            t = (t > 0.f) ? t : NEG_SLOPE * t;
            wv = __expf(t - m);
        }
        lsum += wv;   // deferred: reduced across lanes after the loop
        int e = 0;
        for (; e + 8 <= cl; e += 8) {
            int  s0 = __shfl(sv, e + 0, 32), s1 = __shfl(sv, e + 1, 32);
            int  s2 = __shfl(sv, e + 2, 32), s3 = __shfl(sv, e + 3, 32);
            int  s4 = __shfl(sv, e + 4, 32), s5 = __shfl(sv, e + 5, 32);
            int  s6 = __shfl(sv, e + 6, 32), s7 = __shfl(sv, e + 7, 32);
            float w0 = __shfl(wv, e + 0, 32), w1 = __shfl(wv, e + 1, 32);
            float w2 = __shfl(wv, e + 2, 32), w3 = __shfl(wv, e + 3, 32);
            float w4 = __shfl(wv, e + 4, 32), w5 = __shfl(wv, e + 5, 32);
            float w6 = __shfl(wv, e + 6, 32), w7 = __shfl(wv, e + 7, 32);
            a0 = fmaf(w0, h1c[(size_t)s0 * 128], a0);
            a1 = fmaf(w1, h1c[(size_t)s1 * 128], a1);
            a2 = fmaf(w2, h1c[(size_t)s2 * 128], a2);
            a3 = fmaf(w3, h1c[(size_t)s3 * 128], a3);
            a4 = fmaf(w4, h1c[(size_t)s4 * 128], a4);
            a5 = fmaf(w5, h1c[(size_t)s5 * 128], a5);
            a6 = fmaf(w6, h1c[(size_t)s6 * 128], a6);
            a7 = fmaf(w7, h1c[(size_t)s7 * 128], a7);
        }
        for (; e < cl; ++e) {
            int s = __shfl(sv, e, 32);
            float w = __shfl(wv, e, 32);
            a0 = fmaf(w, h1c[(size_t)s * 128], a0);
        }
    }
#pragma unroll
    for (int off = 16; off; off >>= 1) lsum += __shfl_xor(lsum, off, 32);
    float acc = ((a0 + a1) + (a2 + a3)) + ((a4 + a5) + (a6 + a7));
    float r = acc / lsum + b1[tid];
    r = (r > 0.f) ? r : expm1f(r);           // ELU -> g-row element

    // ---- fused gemm2 + alpha2 epilogue (g never written to HBM) ----
    gs[tid] = r;
    __syncthreads();
    int c = tid & 15, sl = tid >> 4;         // channel, k-slice (0..7)
    float p = 0.f;
#pragma unroll
    for (int kk = 0; kk < 16; ++kk)
        p = fmaf(gs[sl * 16 + kk], W2[(sl * 16 + kk) * 16 + c], p);
    // combine the 4 slices within each wave (lanes c, c+16, c+32, c+48)
    p += __shfl_xor(p, 16);
    p += __shfl_xor(p, 32);
    if ((tid & 63) < 16) red[(tid >> 6) * 16 + c] = p;
    __syncthreads();
    if (tid < 16) {
        float hv = red[tid] + red[16 + tid];
        h2[(size_t)d * 16 + tid] = hv;
        float s1 = hv * a_src2[tid];
        float s2 = hv * a_dst2[tid];
#pragma unroll
        for (int off = 8; off; off >>= 1) {
            s1 += __shfl_xor(s1, off, 16);
            s2 += __shfl_xor(s2, off, 16);
        }
        if (tid == 0) { asrc2[d] = s1; adst2[d] = s2; }
    }
}

// Layer-2 aggregation: 256 threads = 16 nodes x 16 channels; packed (w,s)
// LDS stage + uniform ds_read_b64 broadcast, 8-way unrolled gather.
__global__ __launch_bounds__(256) void agg2_kernel(
    const float* __restrict__ h2, const float* __restrict__ asrc2,
    const float* __restrict__ adst2, const int* __restrict__ rowptr,
    const int* __restrict__ srcs, const float* __restrict__ b2,
    float* __restrict__ out, int N) {
    __shared__ float2 ws2[16][20];
    int tid = threadIdx.x;
    int grp = tid >> 4;
    int d = blockIdx.x * 16 + grp;
    int c = tid & 15;
    if (d >= N) return;
    int start = rowptr[d], end = rowptr[d + 1];
    int deg = end - start;
    float ad = adst2[d];

    float m = -1e30f;
    for (int j = start + c; j < end; j += 16) {
        float t = asrc2[srcs[j]] + ad;
        t = (t > 0.f) ? t : NEG_SLOPE * t;
        m = fmaxf(m, t);
    }
#pragma unroll
    for (int off = 8; off; off >>= 1) m = fmaxf(m, __shfl_xor(m, off, 16));

    float a0 = 0.f, a1 = 0.f, a2 = 0.f, a3 = 0.f;
    float a4 = 0.f, a5 = 0.f, a6 = 0.f, a7 = 0.f;
    float lsum = 0.f;
    const float* h2c = h2 + c;
    for (int cb = 0; cb < deg; cb += 16) {
        int cl = min(16, deg - cb);
        float wv = 0.f; int sv = 0;
        if (c < cl) {
            sv = srcs[start + cb + c];
            float t = asrc2[sv] + ad;
            t = (t > 0.f) ? t : NEG_SLOPE * t;
            wv = __expf(t - m);
        }
        ws2[grp][c] = make_float2(wv, __int_as_float(sv));
        lsum += wv;
        int e = 0;
        for (; e + 8 <= cl; e += 8) {
            float2 p0 = ws2[grp][e + 0], p1 = ws2[grp][e + 1];
            float2 p2 = ws2[grp][e + 2], p3 = ws2[grp][e + 3];
            float2 p4 = ws2[grp][e + 4], p5 = ws2[grp][e + 5];
            float2 p6 = ws2[grp][e + 6], p7 = ws2[grp][e + 7];
            a0 = fmaf(p0.x, h2c[(size_t)__float_as_int(p0.y) * 16], a0);
            a1 = fmaf(p1.x, h2c[(size_t)__float_as_int(p1.y) * 16], a1);
            a2 = fmaf(p2.x, h2c[(size_t)__float_as_int(p2.y) * 16], a2);
            a3 = fmaf(p3.x, h2c[(size_t)__float_as_int(p3.y) * 16], a3);
            a4 = fmaf(p4.x, h2c[(size_t)__float_as_int(p4.y) * 16], a4);
            a5 = fmaf(p5.x, h2c[(size_t)__float_as_int(p5.y) * 16], a5);
            a6 = fmaf(p6.x, h2c[(size_t)__float_as_int(p6.y) * 16], a6);
            a7 = fmaf(p7.x, h2c[(size_t)__float_as_int(p7.y) * 16], a7);
        }
        for (; e < cl; ++e) {
            float2 p = ws2[grp][e];
            a0 = fmaf(p.x, h2c[(size_t)__float_as_int(p.y) * 16], a0);
        }
    }
#pragma unroll
    for (int off = 8; off; off >>= 1) lsum += __shfl_xor(lsum, off, 16);
    float acc = ((a0 + a1) + (a2 + a3)) + ((a4 + a5) + (a6 + a7));
    out[(size_t)d * 16 + c] = acc / lsum + b2[c];
}

// ---------------------------------------------------------------------------
extern "C" void kernel_launch(void* const* d_in, const int* in_sizes, int n_in,
                              void* d_out, int out_size, void* d_ws, size_t ws_size,
                              hipStream_t stream) {
    const float* x      = (const float*)d_in[0];
    const void*  ei     = d_in[1];
    const float* W1     = (const float*)d_in[2];
    const float* a_src1 = (const float*)d_in[3];
    const float* a_dst1 = (const float*)d_in[4];
    const float* b1     = (const float*)d_in[5];
    const float* W2     = (const float*)d_in[6];
    const float* a_src2 = (const float*)d_in[7];
    const float* a_dst2 = (const float*)d_in[8];
    const float* b2     = (const float*)d_in[9];

    const int N  = in_sizes[0] / 128;   // 100000
    const int E  = in_sizes[1] / 2;     // 1600000
    const int ET = E + N;

    char* w = (char*)d_ws;
    size_t off = 0;
    auto alloc = [&](size_t bytes) -> char* {
        char* p = w + off;
        off = (off + bytes + 255) & ~(size_t)255;
        return p;
    };
    float* h1     = (float*)alloc((size_t)N * 128 * 4);
    float* l2buf  = (float*)alloc((size_t)N * 128 * 4);   // h2 + alpha2 (was g)
    float* asrc1  = (float*)alloc((size_t)N * 4 * 4);
    float* adst1  = (float*)alloc((size_t)N * 4 * 4);
    int*   deg    = (int*)alloc((size_t)N * 4);
    int*   cursor = (int*)alloc((size_t)N * 4);
    int*   rowptr = (int*)alloc((size_t)(N + 1) * 4);
    int*   srcs   = (int*)alloc((size_t)ET * 4);
    int*   bsums  = (int*)alloc(4096);
    int*   flag   = (int*)alloc(256);
    float* h2    = l2buf;                 // agg1 reads h1, writes here: no alias
    float* asrc2 = l2buf + (size_t)N * 16;
    float* adst2 = asrc2 + N;

    const int nb = (N + 1023) / 1024;

    detect_fmt_kernel<<<1, 1, 0, stream>>>(ei, flag);
    gemm1_kernel<<<(N + 127) / 128, 256, 0, stream>>>(x, W1, a_src1, a_dst1,
                                                      h1, asrc1, adst1, N);
    deg_init_kernel<<<(N + 255) / 256, 256, 0, stream>>>(deg, cursor, N);
    hist_kernel<<<(E + 255) / 256, 256, 0, stream>>>(ei, deg, E, flag);
    reduce_kernel<<<nb, 256, 0, stream>>>(deg, bsums, N);
    scan_bsums_kernel<<<1, 128, 0, stream>>>(bsums, rowptr, nb, N);
    scan_write_kernel<<<nb, 256, 0, stream>>>(deg, bsums, rowptr, N);
    scatter_kernel<<<(ET + 255) / 256, 256, 0, stream>>>(ei, rowptr, cursor, srcs, E, ET, flag);
    agg1_kernel<<<N, 128, 0, stream>>>(h1, asrc1, adst1, rowptr, srcs, b1,
                                       W2, a_src2, a_dst2, h2, asrc2, adst2, N);
    agg2_kernel<<<(N + 15) / 16, 256, 0, stream>>>(h2, asrc2, adst2, rowptr, srcs, b2, (float*)d_out, N);
}